// Round 1
// baseline (1569.336 us; speedup 1.0000x reference)
//
#include <hip/hip_runtime.h>

typedef __bf16 bf16x8 __attribute__((ext_vector_type(8)));
typedef float f32x4 __attribute__((ext_vector_type(4)));
typedef unsigned short u16;
typedef unsigned int u32;

static constexpr int B = 2, S = 2048, D = 512, H = 8, HD = 64, F = 2048, L = 4, HK = 512, M = 4096;

__device__ __forceinline__ u16 f2bf(float f) {
  u32 u = __float_as_uint(f);
  u = (u + 0x7fffu + ((u >> 16) & 1u)) >> 16;
  return (u16)u;
}

__device__ __forceinline__ f32x4 mfma16(bf16x8 a, bf16x8 b, f32x4 c) {
  return __builtin_amdgcn_mfma_f32_16x16x32_bf16(a, b, c, 0, 0, 0);
}

// ---------------- weight transpose: fp32 [R][C] -> bf16 [C][R], per layer z ----
__global__ __launch_bounds__(256) void wtrans_kernel(const float* __restrict__ in,
                                                     u16* __restrict__ out,
                                                     int R, int C) {
  __shared__ float tile[32][33];
  size_t lo = (size_t)blockIdx.z * R * C;
  in += lo; out += lo;
  int r0 = blockIdx.x * 32, c0 = blockIdx.y * 32;
  int tx = threadIdx.x, ty = threadIdx.y;  // (32,8)
  #pragma unroll
  for (int i = ty; i < 32; i += 8)
    tile[i][tx] = in[(size_t)(r0 + i) * C + c0 + tx];
  __syncthreads();
  #pragma unroll
  for (int i = ty; i < 32; i += 8)
    out[(size_t)(c0 + i) * R + r0 + tx] = f2bf(tile[tx][i]);
}

// ---------------- embedding: h = emb[x] + pos (fp32 master + bf16 shadow) -----
__global__ __launch_bounds__(256) void embed_kernel(const int* __restrict__ x,
                                                    const float* __restrict__ emb,
                                                    const float* __restrict__ pos,
                                                    float* __restrict__ hf,
                                                    u16* __restrict__ hb) {
  int idx = blockIdx.x * 256 + threadIdx.x;  // over M * D/4
  int dc = idx & 127;                        // D/4 = 128
  int bs = idx >> 7;
  int s = bs & (S - 1);
  int tok = x[bs];
  float4 e = ((const float4*)(emb + (size_t)tok * D))[dc];
  float4 p = ((const float4*)(pos + (size_t)s * D))[dc];
  float4 v;
  v.x = e.x + p.x; v.y = e.y + p.y; v.z = e.z + p.z; v.w = e.w + p.w;
  ((float4*)hf)[idx] = v;
  ushort4 u;
  u.x = f2bf(v.x); u.y = f2bf(v.y); u.z = f2bf(v.z); u.w = f2bf(v.w);
  ((ushort4*)hb)[idx] = u;
}

// ---------------- GEMM: out_bf16 = [relu](A_bf16[M][Kd] @ WT[N][Kd]^T + bias) -
__global__ __launch_bounds__(256) void gemm_bf16_kernel(const u16* __restrict__ A,
                                                        const u16* __restrict__ WT,
                                                        const float* __restrict__ bias,
                                                        u16* __restrict__ out,
                                                        int N_, int Kd, int relu) {
  int lane = threadIdx.x & 63, w = threadIdx.x >> 6;
  int lr = lane & 15, lg = lane >> 4;
  int r0 = blockIdx.x * 64 + w * 16;
  int c0 = blockIdx.y * 64;
  f32x4 acc[4] = {};
  const u16* arow = A + (size_t)(r0 + lr) * Kd + lg * 8;
  for (int k0 = 0; k0 < Kd; k0 += 32) {
    bf16x8 a = *(const bf16x8*)(arow + k0);
    #pragma unroll
    for (int cn = 0; cn < 4; cn++) {
      const u16* brow = WT + (size_t)(c0 + cn * 16 + lr) * Kd + k0 + lg * 8;
      bf16x8 b = *(const bf16x8*)brow;
      acc[cn] = mfma16(a, b, acc[cn]);
    }
  }
  #pragma unroll
  for (int cn = 0; cn < 4; cn++) {
    int col = c0 + cn * 16 + lr;
    float bv = bias[col];
    #pragma unroll
    for (int r = 0; r < 4; r++) {
      int row = r0 + lg * 4 + r;
      float v = acc[cn][r] + bv;
      if (relu) v = fmaxf(v, 0.f);
      out[(size_t)row * N_ + col] = f2bf(v);
    }
  }
}

// ---------------- GEMM + residual into fp32 master (N = D = 512) -------------
__global__ __launch_bounds__(256) void gemm_resid_kernel(const u16* __restrict__ A,
                                                         const u16* __restrict__ WT,
                                                         const float* __restrict__ bias,
                                                         float* __restrict__ hf,
                                                         u16* __restrict__ hb,
                                                         int Kd) {
  int lane = threadIdx.x & 63, w = threadIdx.x >> 6;
  int lr = lane & 15, lg = lane >> 4;
  int r0 = blockIdx.x * 64 + w * 16;
  int c0 = blockIdx.y * 64;
  f32x4 acc[4] = {};
  const u16* arow = A + (size_t)(r0 + lr) * Kd + lg * 8;
  for (int k0 = 0; k0 < Kd; k0 += 32) {
    bf16x8 a = *(const bf16x8*)(arow + k0);
    #pragma unroll
    for (int cn = 0; cn < 4; cn++) {
      const u16* brow = WT + (size_t)(c0 + cn * 16 + lr) * Kd + k0 + lg * 8;
      bf16x8 b = *(const bf16x8*)brow;
      acc[cn] = mfma16(a, b, acc[cn]);
    }
  }
  #pragma unroll
  for (int cn = 0; cn < 4; cn++) {
    int col = c0 + cn * 16 + lr;
    float bv = bias[col];
    #pragma unroll
    for (int r = 0; r < 4; r++) {
      int row = r0 + lg * 4 + r;
      size_t idx = (size_t)row * D + col;
      float v = hf[idx] + acc[cn][r] + bv;
      hf[idx] = v;
      hb[idx] = f2bf(v);
    }
  }
}

// ---------------- V transpose: [B*S][HK] -> [B*H][64][S] ----------------------
__global__ __launch_bounds__(256) void vtrans_kernel(const u16* __restrict__ v,
                                                     u16* __restrict__ vt) {
  __shared__ u16 tile[64][65];
  int bh = blockIdx.x, b = bh >> 3, h = bh & 7;
  int s0 = blockIdx.y * 64;
  int t = threadIdx.x;
  union V16 { uint4 v4[2]; u16 e[16]; };
  {
    int sl = t >> 2, cc = (t & 3) * 16;
    const u16* src = v + (size_t)(b * S + s0 + sl) * HK + h * 64 + cc;
    V16 tv;
    tv.v4[0] = *(const uint4*)src;
    tv.v4[1] = *(const uint4*)(src + 8);
    #pragma unroll
    for (int i = 0; i < 16; i++) tile[sl][cc + i] = tv.e[i];
  }
  __syncthreads();
  {
    int kd = t >> 2, sc = (t & 3) * 16;
    V16 tv;
    #pragma unroll
    for (int i = 0; i < 16; i++) tv.e[i] = tile[sc + i][kd];
    u16* dst = vt + ((size_t)bh * 64 + kd) * S + s0 + sc;
    *(uint4*)dst = tv.v4[0];
    *(uint4*)(dst + 8) = tv.v4[1];
  }
}

// ---------------- flash attention: per (b,h), 64 q-rows per block -------------
__global__ __launch_bounds__(256) void attn_kernel(const u16* __restrict__ q,
                                                   const u16* __restrict__ k,
                                                   const u16* __restrict__ vt,
                                                   u16* __restrict__ o) {
  __shared__ u16 p_lds[4][16][32];
  int bh = blockIdx.x, b = bh >> 3, h = bh & 7;
  int lane = threadIdx.x & 63, w = threadIdx.x >> 6;
  int lr = lane & 15, lg = lane >> 4;
  int qr0 = blockIdx.y * 64 + w * 16;

  const u16* qbase = q + (size_t)(b * S + qr0 + lr) * HK + h * 64 + lg * 8;
  bf16x8 qa0 = *(const bf16x8*)qbase;
  bf16x8 qa1 = *(const bf16x8*)(qbase + 32);

  f32x4 oacc[4] = {};
  float mrow[4] = {-3.0e38f, -3.0e38f, -3.0e38f, -3.0e38f};
  float lrow[4] = {0.f, 0.f, 0.f, 0.f};
  int qhi = qr0 + 15;
  const u16* kbase = k + (size_t)(b * S) * HK + h * 64;
  const u16* vbase = vt + (size_t)bh * 64 * S;

  for (int kv0 = 0; kv0 <= qhi; kv0 += 32) {
    f32x4 sc[2];
    #pragma unroll
    for (int cn = 0; cn < 2; cn++) {
      const u16* kr = kbase + (size_t)(kv0 + cn * 16 + lr) * HK + lg * 8;
      bf16x8 kb0 = *(const bf16x8*)kr;
      bf16x8 kb1 = *(const bf16x8*)(kr + 32);
      f32x4 t = {};
      t = mfma16(qa0, kb0, t);
      t = mfma16(qa1, kb1, t);
      sc[cn] = t;
    }
    #pragma unroll
    for (int r = 0; r < 4; r++) {
      int qrow = qr0 + lg * 4 + r;
      float s0 = sc[0][r] * 0.125f;
      float s1 = sc[1][r] * 0.125f;
      if (kv0 + lr > qrow) s0 = -1e30f;
      if (kv0 + 16 + lr > qrow) s1 = -1e30f;
      float mx = fmaxf(s0, s1);
      #pragma unroll
      for (int off = 1; off < 16; off <<= 1) mx = fmaxf(mx, __shfl_xor(mx, off));
      float mnew = fmaxf(mrow[r], mx);
      float corr = __expf(mrow[r] - mnew);
      float p0 = __expf(s0 - mnew);
      float p1 = __expf(s1 - mnew);
      float ps = p0 + p1;
      #pragma unroll
      for (int off = 1; off < 16; off <<= 1) ps += __shfl_xor(ps, off);
      lrow[r] = lrow[r] * corr + ps;
      mrow[r] = mnew;
      oacc[0][r] *= corr; oacc[1][r] *= corr; oacc[2][r] *= corr; oacc[3][r] *= corr;
      p_lds[w][lg * 4 + r][lr] = f2bf(p0);
      p_lds[w][lg * 4 + r][16 + lr] = f2bf(p1);
    }
    bf16x8 pa = *(const bf16x8*)&p_lds[w][lr][lg * 8];
    #pragma unroll
    for (int cn = 0; cn < 4; cn++) {
      bf16x8 vb = *(const bf16x8*)(vbase + (size_t)(cn * 16 + lr) * S + kv0 + lg * 8);
      oacc[cn] = mfma16(pa, vb, oacc[cn]);
    }
  }
  #pragma unroll
  for (int cn = 0; cn < 4; cn++) {
    #pragma unroll
    for (int r = 0; r < 4; r++) {
      float val = oacc[cn][r] / lrow[r];
      o[(size_t)(b * S + qr0 + lg * 4 + r) * HK + h * 64 + cn * 16 + lr] = f2bf(val);
    }
  }
}

extern "C" void kernel_launch(void* const* d_in, const int* in_sizes, int n_in,
                              void* d_out, int out_size, void* d_ws, size_t ws_size,
                              hipStream_t stream) {
  const int* x = (const int*)d_in[0];
  const float* emb = (const float*)d_in[1];
  const float* pos = (const float*)d_in[2];
  const float* Wq = (const float*)d_in[3];
  const float* bq = (const float*)d_in[4];
  const float* Wk = (const float*)d_in[5];
  const float* bk = (const float*)d_in[6];
  const float* Wv = (const float*)d_in[7];
  const float* bv = (const float*)d_in[8];
  const float* Wo = (const float*)d_in[9];
  const float* bo = (const float*)d_in[10];
  const float* W1 = (const float*)d_in[11];
  const float* b1 = (const float*)d_in[12];
  const float* W2 = (const float*)d_in[13];
  const float* b2 = (const float*)d_in[14];
  float* hf = (float*)d_out;

  char* p = (char*)d_ws;
  const size_t SZ_MD = (size_t)M * D * 2;  // 4MB
  u16* h_bf = (u16*)p;  p += SZ_MD;
  u16* q_bf = (u16*)p;  p += SZ_MD;
  u16* k_bf = (u16*)p;  p += SZ_MD;
  u16* v_bf = (u16*)p;  p += SZ_MD;
  u16* vt_bf = (u16*)p; p += SZ_MD;
  u16* o_bf = (u16*)p;  p += SZ_MD;
  u16* ff_bf = (u16*)p; p += (size_t)M * F * 2;
  u16* WqT = (u16*)p;   p += (size_t)L * D * HK * 2;
  u16* WkT = (u16*)p;   p += (size_t)L * D * HK * 2;
  u16* WvT = (u16*)p;   p += (size_t)L * D * HK * 2;
  u16* WoT = (u16*)p;   p += (size_t)L * HK * D * 2;
  u16* W1T = (u16*)p;   p += (size_t)L * D * F * 2;
  u16* W2T = (u16*)p;   p += (size_t)L * F * D * 2;

  dim3 tb(32, 8);
  wtrans_kernel<<<dim3(D / 32, HK / 32, L), tb, 0, stream>>>(Wq, WqT, D, HK);
  wtrans_kernel<<<dim3(D / 32, HK / 32, L), tb, 0, stream>>>(Wk, WkT, D, HK);
  wtrans_kernel<<<dim3(D / 32, HK / 32, L), tb, 0, stream>>>(Wv, WvT, D, HK);
  wtrans_kernel<<<dim3(HK / 32, D / 32, L), tb, 0, stream>>>(Wo, WoT, HK, D);
  wtrans_kernel<<<dim3(D / 32, F / 32, L), tb, 0, stream>>>(W1, W1T, D, F);
  wtrans_kernel<<<dim3(F / 32, D / 32, L), tb, 0, stream>>>(W2, W2T, F, D);

  embed_kernel<<<(M * D / 4) / 256, 256, 0, stream>>>(x, emb, pos, hf, h_bf);

  for (int l = 0; l < L; ++l) {
    gemm_bf16_kernel<<<dim3(M / 64, HK / 64), 256, 0, stream>>>(
        h_bf, WqT + (size_t)l * D * HK, bq + l * HK, q_bf, HK, D, 0);
    gemm_bf16_kernel<<<dim3(M / 64, HK / 64), 256, 0, stream>>>(
        h_bf, WkT + (size_t)l * D * HK, bk + l * HK, k_bf, HK, D, 0);
    gemm_bf16_kernel<<<dim3(M / 64, HK / 64), 256, 0, stream>>>(
        h_bf, WvT + (size_t)l * D * HK, bv + l * HK, v_bf, HK, D, 0);
    vtrans_kernel<<<dim3(B * H, S / 64), 256, 0, stream>>>(v_bf, vt_bf);
    attn_kernel<<<dim3(B * H, S / 64), 256, 0, stream>>>(q_bf, k_bf, vt_bf, o_bf);
    gemm_resid_kernel<<<dim3(M / 64, D / 64), 256, 0, stream>>>(
        o_bf, WoT + (size_t)l * HK * D, bo + l * D, hf, h_bf, HK);
    gemm_bf16_kernel<<<dim3(M / 64, F / 64), 256, 0, stream>>>(
        h_bf, W1T + (size_t)l * D * F, b1 + l * F, ff_bf, F, D, 1);
    gemm_resid_kernel<<<dim3(M / 64, D / 64), 256, 0, stream>>>(
        ff_bf, W2T + (size_t)l * F * D, b2 + l * D, hf, h_bf, F);
  }
}

// Round 3
// 883.410 us; speedup vs baseline: 1.7765x; 1.7765x over previous
//
#include <hip/hip_runtime.h>

typedef __bf16 bf16x8 __attribute__((ext_vector_type(8)));
typedef float f32x4 __attribute__((ext_vector_type(4)));
typedef unsigned short u16;
typedef unsigned int u32;

static constexpr int B = 2, S = 2048, D = 512, H = 8, HD = 64, F = 2048, L = 4, HK = 512, M = 4096;

__device__ __forceinline__ u16 f2bf(float f) {
  u32 u = __float_as_uint(f);
  u = (u + 0x7fffu + ((u >> 16) & 1u)) >> 16;
  return (u16)u;
}

__device__ __forceinline__ f32x4 mfma16(bf16x8 a, bf16x8 b, f32x4 c) {
  return __builtin_amdgcn_mfma_f32_16x16x32_bf16(a, b, c, 0, 0, 0);
}

__device__ __forceinline__ void gload_lds16(const u16* g, u16* l) {
  __builtin_amdgcn_global_load_lds((const __attribute__((address_space(1))) void*)g,
                                   (__attribute__((address_space(3))) void*)l, 16, 0, 0);
}

// ---------------- weight transpose: fp32 [R][C] -> bf16 [C][R] ----------------
__global__ __launch_bounds__(256) void wtrans_kernel(const float* __restrict__ in,
                                                     u16* __restrict__ out,
                                                     int R, int C, int ostride) {
  __shared__ float tile[32][33];
  in += (size_t)blockIdx.z * R * C;
  out += (size_t)blockIdx.z * ostride;
  int r0 = blockIdx.x * 32, c0 = blockIdx.y * 32;
  int tx = threadIdx.x, ty = threadIdx.y;  // (32,8)
  #pragma unroll
  for (int i = ty; i < 32; i += 8)
    tile[i][tx] = in[(size_t)(r0 + i) * C + c0 + tx];
  __syncthreads();
  #pragma unroll
  for (int i = ty; i < 32; i += 8)
    out[(size_t)(c0 + i) * R + r0 + tx] = f2bf(tile[tx][i]);
}

// ---------------- embedding: h = emb[x] + pos (fp32 master + bf16 shadow) -----
__global__ __launch_bounds__(256) void embed_kernel(const int* __restrict__ x,
                                                    const float* __restrict__ emb,
                                                    const float* __restrict__ pos,
                                                    float* __restrict__ hf,
                                                    u16* __restrict__ hb) {
  int idx = blockIdx.x * 256 + threadIdx.x;  // over M * D/4
  int dc = idx & 127;                        // D/4 = 128
  int bs = idx >> 7;
  int s = bs & (S - 1);
  int tok = x[bs];
  float4 e = ((const float4*)(emb + (size_t)tok * D))[dc];
  float4 p = ((const float4*)(pos + (size_t)s * D))[dc];
  float4 v;
  v.x = e.x + p.x; v.y = e.y + p.y; v.z = e.z + p.z; v.w = e.w + p.w;
  ((float4*)hf)[idx] = v;
  ushort4 u;
  u.x = f2bf(v.x); u.y = f2bf(v.y); u.z = f2bf(v.z); u.w = f2bf(v.w);
  ((ushort4*)hb)[idx] = u;
}

// ---------------- m97-style GEMM core: BM x 128 tile, BK=32, global_load_lds --
// A: bf16 [M][KD] row-major; Wt: bf16 [N][KD] row-major (pre-transposed weights)
template <int BM, int KD>
__device__ __forceinline__ void gemm_core(const u16* __restrict__ A,
                                          const u16* __restrict__ Wt,
                                          u16* lds, f32x4 (&acc)[4][4]) {
  constexpr int WN = (BM == 128) ? 2 : 4;  // waves along N
  constexpr int NI = 8 / WN;               // 16-col frags per wave
  constexpr int MI = 4;                    // 16-row frags per wave
  const int t = threadIdx.x;
  const int lane = t & 63, w = t >> 6;
  const int lr = lane & 15, lg = lane >> 4;
  const int wm = w / WN, wn = w % WN;
  const int r0 = blockIdx.x * BM, c0 = blockIdx.y * 128;
  u16* ldsA = lds;                 // [BM][32]
  u16* ldsB = lds + BM * 32;       // [128][32]
  const int srow = t >> 2, scol = (t & 3) * 8;
  const u16* gA = A + (size_t)(r0 + srow) * KD + scol;
  const u16* gB = Wt + (size_t)(c0 + srow) * KD + scol;
  const int ldsw = w * 512;        // 1 KB per wave (elements)

  for (int k0 = 0; k0 < KD; k0 += 32) {
    gload_lds16(gA + k0, ldsA + ldsw);
    if (BM == 128) gload_lds16(gA + (size_t)64 * KD + k0, ldsA + 2048 + ldsw);
    gload_lds16(gB + k0, ldsB + ldsw);
    gload_lds16(gB + (size_t)64 * KD + k0, ldsB + 2048 + ldsw);
    __syncthreads();
    bf16x8 a[MI], b[NI];
    #pragma unroll
    for (int i = 0; i < MI; i++)
      a[i] = *(const bf16x8*)(ldsA + (wm * 64 + i * 16 + lr) * 32 + lg * 8);
    #pragma unroll
    for (int j = 0; j < NI; j++)
      b[j] = *(const bf16x8*)(ldsB + (wn * NI * 16 + j * 16 + lr) * 32 + lg * 8);
    #pragma unroll
    for (int i = 0; i < MI; i++)
      #pragma unroll
      for (int j = 0; j < NI; j++)
        acc[i][j] = mfma16(a[i], b[j], acc[i][j]);
    __syncthreads();
  }
}

// ---------------- fused QKV GEMM: N=1536 -> q/k/v buffers ---------------------
__global__ __launch_bounds__(256) void gemm_qkv_kernel(const u16* __restrict__ A,
                                                       const u16* __restrict__ Wt,
                                                       const float* __restrict__ bq,
                                                       const float* __restrict__ bk,
                                                       const float* __restrict__ bv,
                                                       u16* __restrict__ q,
                                                       u16* __restrict__ k,
                                                       u16* __restrict__ v) {
  __shared__ u16 lds[8192];
  f32x4 acc[4][4] = {};
  gemm_core<128, 512>(A, Wt, lds, acc);
  const int lane = threadIdx.x & 63, w = threadIdx.x >> 6;
  const int lr = lane & 15, lg = lane >> 4;
  const int wm = w >> 1, wn = w & 1;
  const int r0 = blockIdx.x * 128, c0 = blockIdx.y * 128;
  #pragma unroll
  for (int j = 0; j < 4; j++) {
    int col = c0 + wn * 64 + j * 16 + lr;
    int sel = col >> 9, cc = col & 511;
    u16* outp = (sel == 0) ? q : (sel == 1) ? k : v;
    const float* bp = (sel == 0) ? bq : (sel == 1) ? bk : bv;
    float bias = bp[cc];
    #pragma unroll
    for (int i = 0; i < 4; i++) {
      int rbase = r0 + wm * 64 + i * 16 + lg * 4;
      #pragma unroll
      for (int r = 0; r < 4; r++)
        outp[(size_t)(rbase + r) * 512 + cc] = f2bf(acc[i][j][r] + bias);
    }
  }
}

// ---------------- FF1 GEMM: relu(h @ W1 + b1), N=2048 ------------------------
__global__ __launch_bounds__(256) void gemm_ff1_kernel(const u16* __restrict__ A,
                                                       const u16* __restrict__ Wt,
                                                       const float* __restrict__ bias,
                                                       u16* __restrict__ out) {
  __shared__ u16 lds[8192];
  f32x4 acc[4][4] = {};
  gemm_core<128, 512>(A, Wt, lds, acc);
  const int lane = threadIdx.x & 63, w = threadIdx.x >> 6;
  const int lr = lane & 15, lg = lane >> 4;
  const int wm = w >> 1, wn = w & 1;
  const int r0 = blockIdx.x * 128, c0 = blockIdx.y * 128;
  #pragma unroll
  for (int j = 0; j < 4; j++) {
    int col = c0 + wn * 64 + j * 16 + lr;
    float bv = bias[col];
    #pragma unroll
    for (int i = 0; i < 4; i++) {
      int rbase = r0 + wm * 64 + i * 16 + lg * 4;
      #pragma unroll
      for (int r = 0; r < 4; r++)
        out[(size_t)(rbase + r) * F + col] = f2bf(fmaxf(acc[i][j][r] + bv, 0.f));
    }
  }
}

// ---------------- residual GEMM: hf += A@W + b (N=512), BM=64 -----------------
template <int KD>
__global__ __launch_bounds__(256) void gemm_resid_kernel(const u16* __restrict__ A,
                                                         const u16* __restrict__ Wt,
                                                         const float* __restrict__ bias,
                                                         float* __restrict__ hf,
                                                         u16* __restrict__ hb) {
  __shared__ u16 lds[6144];
  f32x4 acc[4][4] = {};
  gemm_core<64, KD>(A, Wt, lds, acc);
  const int lane = threadIdx.x & 63, w = threadIdx.x >> 6;
  const int lr = lane & 15, lg = lane >> 4;
  const int wn = w;  // 1x4 wave grid
  const int r0 = blockIdx.x * 64, c0 = blockIdx.y * 128;
  #pragma unroll
  for (int j = 0; j < 2; j++) {
    int col = c0 + wn * 32 + j * 16 + lr;
    float bv = bias[col];
    #pragma unroll
    for (int i = 0; i < 4; i++) {
      int rbase = r0 + i * 16 + lg * 4;
      #pragma unroll
      for (int r = 0; r < 4; r++) {
        size_t idx = (size_t)(rbase + r) * D + col;
        float v = hf[idx] + acc[i][j][r] + bv;
        hf[idx] = v;
        hb[idx] = f2bf(v);
      }
    }
  }
}

// ---------------- V transpose: [B*S][HK] -> [B*H][64][S] ----------------------
__global__ __launch_bounds__(256) void vtrans_kernel(const u16* __restrict__ v,
                                                     u16* __restrict__ vt) {
  __shared__ u16 tile[64][65];
  int bh = blockIdx.x, b = bh >> 3, h = bh & 7;
  int s0 = blockIdx.y * 64;
  int t = threadIdx.x;
  union V16 { uint4 v4[2]; u16 e[16]; };
  {
    int sl = t >> 2, cc = (t & 3) * 16;
    const u16* src = v + (size_t)(b * S + s0 + sl) * HK + h * 64 + cc;
    V16 tv;
    tv.v4[0] = *(const uint4*)src;
    tv.v4[1] = *(const uint4*)(src + 8);
    #pragma unroll
    for (int i = 0; i < 16; i++) tile[sl][cc + i] = tv.e[i];
  }
  __syncthreads();
  {
    int kd = t >> 2, sc = (t & 3) * 16;
    V16 tv;
    #pragma unroll
    for (int i = 0; i < 16; i++) tv.e[i] = tile[sc + i][kd];
    u16* dst = vt + ((size_t)bh * 64 + kd) * S + s0 + sc;
    *(uint4*)dst = tv.v4[0];
    *(uint4*)(dst + 8) = tv.v4[1];
  }
}

// ---------------- flash attention: per (b,h), 64 q-rows per block -------------
__global__ __launch_bounds__(256) void attn_kernel(const u16* __restrict__ q,
                                                   const u16* __restrict__ k,
                                                   const u16* __restrict__ vt,
                                                   u16* __restrict__ o) {
  __shared__ u16 p_lds[4][16][32];
  int bh = blockIdx.x, b = bh >> 3, h = bh & 7;
  int lane = threadIdx.x & 63, w = threadIdx.x >> 6;
  int lr = lane & 15, lg = lane >> 4;
  int qr0 = blockIdx.y * 64 + w * 16;

  const u16* qbase = q + (size_t)(b * S + qr0 + lr) * HK + h * 64 + lg * 8;
  bf16x8 qa0 = *(const bf16x8*)qbase;
  bf16x8 qa1 = *(const bf16x8*)(qbase + 32);

  f32x4 oacc[4] = {};
  float mrow[4] = {-3.0e38f, -3.0e38f, -3.0e38f, -3.0e38f};
  float lrow[4] = {0.f, 0.f, 0.f, 0.f};
  int qhi = qr0 + 15;
  const u16* kbase = k + (size_t)(b * S) * HK + h * 64;
  const u16* vbase = vt + (size_t)bh * 64 * S;

  for (int kv0 = 0; kv0 <= qhi; kv0 += 32) {
    f32x4 sc[2];
    #pragma unroll
    for (int cn = 0; cn < 2; cn++) {
      const u16* kr = kbase + (size_t)(kv0 + cn * 16 + lr) * HK + lg * 8;
      bf16x8 kb0 = *(const bf16x8*)kr;
      bf16x8 kb1 = *(const bf16x8*)(kr + 32);
      f32x4 t = {};
      t = mfma16(qa0, kb0, t);
      t = mfma16(qa1, kb1, t);
      sc[cn] = t;
    }
    #pragma unroll
    for (int r = 0; r < 4; r++) {
      int qrow = qr0 + lg * 4 + r;
      float s0 = sc[0][r] * 0.125f;
      float s1 = sc[1][r] * 0.125f;
      if (kv0 + lr > qrow) s0 = -1e30f;
      if (kv0 + 16 + lr > qrow) s1 = -1e30f;
      float mx = fmaxf(s0, s1);
      #pragma unroll
      for (int off = 1; off < 16; off <<= 1) mx = fmaxf(mx, __shfl_xor(mx, off));
      float mnew = fmaxf(mrow[r], mx);
      float corr = __expf(mrow[r] - mnew);
      float p0 = __expf(s0 - mnew);
      float p1 = __expf(s1 - mnew);
      float ps = p0 + p1;
      #pragma unroll
      for (int off = 1; off < 16; off <<= 1) ps += __shfl_xor(ps, off);
      lrow[r] = lrow[r] * corr + ps;
      mrow[r] = mnew;
      oacc[0][r] *= corr; oacc[1][r] *= corr; oacc[2][r] *= corr; oacc[3][r] *= corr;
      p_lds[w][lg * 4 + r][lr] = f2bf(p0);
      p_lds[w][lg * 4 + r][16 + lr] = f2bf(p1);
    }
    bf16x8 pa = *(const bf16x8*)&p_lds[w][lr][lg * 8];
    #pragma unroll
    for (int cn = 0; cn < 4; cn++) {
      bf16x8 vb = *(const bf16x8*)(vbase + (size_t)(cn * 16 + lr) * S + kv0 + lg * 8);
      oacc[cn] = mfma16(pa, vb, oacc[cn]);
    }
  }
  #pragma unroll
  for (int cn = 0; cn < 4; cn++) {
    #pragma unroll
    for (int r = 0; r < 4; r++) {
      float val = oacc[cn][r] / lrow[r];
      o[(size_t)(b * S + qr0 + lg * 4 + r) * HK + h * 64 + cn * 16 + lr] = f2bf(val);
    }
  }
}

extern "C" void kernel_launch(void* const* d_in, const int* in_sizes, int n_in,
                              void* d_out, int out_size, void* d_ws, size_t ws_size,
                              hipStream_t stream) {
  const int* x = (const int*)d_in[0];
  const float* emb = (const float*)d_in[1];
  const float* pos = (const float*)d_in[2];
  const float* Wq = (const float*)d_in[3];
  const float* bq = (const float*)d_in[4];
  const float* Wk = (const float*)d_in[5];
  const float* bk = (const float*)d_in[6];
  const float* Wv = (const float*)d_in[7];
  const float* bv = (const float*)d_in[8];
  const float* Wo = (const float*)d_in[9];
  const float* bo = (const float*)d_in[10];
  const float* W1 = (const float*)d_in[11];
  const float* b1 = (const float*)d_in[12];
  const float* W2 = (const float*)d_in[13];
  const float* b2 = (const float*)d_in[14];
  float* hf = (float*)d_out;

  char* p = (char*)d_ws;
  const size_t SZ_MD = (size_t)M * D * 2;  // 4MB
  u16* h_bf = (u16*)p;  p += SZ_MD;
  u16* q_bf = (u16*)p;  p += SZ_MD;
  u16* k_bf = (u16*)p;  p += SZ_MD;
  u16* v_bf = (u16*)p;  p += SZ_MD;
  u16* vt_bf = (u16*)p; p += SZ_MD;
  u16* o_bf = (u16*)p;  p += SZ_MD;
  u16* ff_bf = (u16*)p; p += (size_t)M * F * 2;
  u16* WqkvT = (u16*)p; p += (size_t)L * D * (3 * HK) * 2;  // [L][1536][512]
  u16* WoT = (u16*)p;   p += (size_t)L * HK * D * 2;
  u16* W1T = (u16*)p;   p += (size_t)L * D * F * 2;
  u16* W2T = (u16*)p;   p += (size_t)L * F * D * 2;

  dim3 tb(32, 8);
  const int QKV_L = 3 * HK * D;  // per-layer stride of fused qkv weights
  wtrans_kernel<<<dim3(D / 32, HK / 32, L), tb, 0, stream>>>(Wq, WqkvT, D, HK, QKV_L);
  wtrans_kernel<<<dim3(D / 32, HK / 32, L), tb, 0, stream>>>(Wk, WqkvT + HK * D, D, HK, QKV_L);
  wtrans_kernel<<<dim3(D / 32, HK / 32, L), tb, 0, stream>>>(Wv, WqkvT + 2 * HK * D, D, HK, QKV_L);
  wtrans_kernel<<<dim3(HK / 32, D / 32, L), tb, 0, stream>>>(Wo, WoT, HK, D, HK * D);
  wtrans_kernel<<<dim3(D / 32, F / 32, L), tb, 0, stream>>>(W1, W1T, D, F, D * F);
  wtrans_kernel<<<dim3(F / 32, D / 32, L), tb, 0, stream>>>(W2, W2T, F, D, F * D);

  embed_kernel<<<(M * D / 4) / 256, 256, 0, stream>>>(x, emb, pos, hf, h_bf);

  for (int l = 0; l < L; ++l) {
    gemm_qkv_kernel<<<dim3(M / 128, (3 * HK) / 128), 256, 0, stream>>>(
        h_bf, WqkvT + (size_t)l * QKV_L, bq + l * HK, bk + l * HK, bv + l * HK,
        q_bf, k_bf, v_bf);
    vtrans_kernel<<<dim3(B * H, S / 64), 256, 0, stream>>>(v_bf, vt_bf);
    attn_kernel<<<dim3(B * H, S / 64), 256, 0, stream>>>(q_bf, k_bf, vt_bf, o_bf);
    gemm_resid_kernel<512><<<dim3(M / 64, D / 128), 256, 0, stream>>>(
        o_bf, WoT + (size_t)l * HK * D, bo + l * D, hf, h_bf);
    gemm_ff1_kernel<<<dim3(M / 128, F / 128), 256, 0, stream>>>(
        h_bf, W1T + (size_t)l * D * F, b1 + l * F, ff_bf);
    gemm_resid_kernel<2048><<<dim3(M / 64, D / 128), 256, 0, stream>>>(
        ff_bf, W2T + (size_t)l * F * D, b2 + l * D, hf, h_bf);
  }
}

// Round 4
// 851.124 us; speedup vs baseline: 1.8438x; 1.0379x over previous
//
#include <hip/hip_runtime.h>

typedef __bf16 bf16x8 __attribute__((ext_vector_type(8)));
typedef float f32x4 __attribute__((ext_vector_type(4)));
typedef float f32x16 __attribute__((ext_vector_type(16)));
typedef unsigned short u16;
typedef unsigned int u32;

static constexpr int B = 2, S = 2048, D = 512, H = 8, HD = 64, F = 2048, L = 4, HK = 512, M = 4096;

__device__ __forceinline__ u16 f2bf(float f) {
  u32 u = __float_as_uint(f);
  u = (u + 0x7fffu + ((u >> 16) & 1u)) >> 16;
  return (u16)u;
}

__device__ __forceinline__ u32 pk2(float lo, float hi) {
  return (u32)f2bf(lo) | ((u32)f2bf(hi) << 16);
}

__device__ __forceinline__ f32x4 mfma16(bf16x8 a, bf16x8 b, f32x4 c) {
  return __builtin_amdgcn_mfma_f32_16x16x32_bf16(a, b, c, 0, 0, 0);
}

__device__ __forceinline__ f32x16 mfma32(bf16x8 a, bf16x8 b, f32x16 c) {
  return __builtin_amdgcn_mfma_f32_32x32x16_bf16(a, b, c, 0, 0, 0);
}

__device__ __forceinline__ void gload_lds16(const u16* g, u16* l) {
  __builtin_amdgcn_global_load_lds((const __attribute__((address_space(1))) void*)g,
                                   (__attribute__((address_space(3))) void*)l, 16, 0, 0);
}

// ---------------- weight transpose: fp32 [R][C] -> bf16 [C][R] ----------------
__global__ __launch_bounds__(256) void wtrans_kernel(const float* __restrict__ in,
                                                     u16* __restrict__ out,
                                                     int R, int C, int ostride) {
  __shared__ float tile[32][33];
  in += (size_t)blockIdx.z * R * C;
  out += (size_t)blockIdx.z * ostride;
  int r0 = blockIdx.x * 32, c0 = blockIdx.y * 32;
  int tx = threadIdx.x, ty = threadIdx.y;  // (32,8)
  #pragma unroll
  for (int i = ty; i < 32; i += 8)
    tile[i][tx] = in[(size_t)(r0 + i) * C + c0 + tx];
  __syncthreads();
  #pragma unroll
  for (int i = ty; i < 32; i += 8)
    out[(size_t)(c0 + i) * R + r0 + tx] = f2bf(tile[tx][i]);
}

// ---------------- embedding: h = emb[x] + pos (fp32 master + bf16 shadow) -----
__global__ __launch_bounds__(256) void embed_kernel(const int* __restrict__ x,
                                                    const float* __restrict__ emb,
                                                    const float* __restrict__ pos,
                                                    float* __restrict__ hf,
                                                    u16* __restrict__ hb) {
  int idx = blockIdx.x * 256 + threadIdx.x;  // over M * D/4
  int dc = idx & 127;                        // D/4 = 128
  int bs = idx >> 7;
  int s = bs & (S - 1);
  int tok = x[bs];
  float4 e = ((const float4*)(emb + (size_t)tok * D))[dc];
  float4 p = ((const float4*)(pos + (size_t)s * D))[dc];
  float4 v;
  v.x = e.x + p.x; v.y = e.y + p.y; v.z = e.z + p.z; v.w = e.w + p.w;
  ((float4*)hf)[idx] = v;
  ushort4 u;
  u.x = f2bf(v.x); u.y = f2bf(v.y); u.z = f2bf(v.z); u.w = f2bf(v.w);
  ((ushort4*)hb)[idx] = u;
}

// ---------------- m97-style GEMM core: BM x 128 tile, BK=32, global_load_lds --
template <int BM, int KD>
__device__ __forceinline__ void gemm_core(const u16* __restrict__ A,
                                          const u16* __restrict__ Wt,
                                          u16* lds, f32x4 (&acc)[4][4]) {
  constexpr int WN = (BM == 128) ? 2 : 4;  // waves along N
  constexpr int NI = 8 / WN;               // 16-col frags per wave
  constexpr int MI = 4;                    // 16-row frags per wave
  const int t = threadIdx.x;
  const int lane = t & 63, w = t >> 6;
  const int lr = lane & 15, lg = lane >> 4;
  const int wm = w / WN, wn = w % WN;
  const int r0 = blockIdx.x * BM, c0 = blockIdx.y * 128;
  u16* ldsA = lds;                 // [BM][32]
  u16* ldsB = lds + BM * 32;       // [128][32]
  const int srow = t >> 2, scol = (t & 3) * 8;
  const u16* gA = A + (size_t)(r0 + srow) * KD + scol;
  const u16* gB = Wt + (size_t)(c0 + srow) * KD + scol;
  const int ldsw = w * 512;        // 1 KB per wave (elements)

  for (int k0 = 0; k0 < KD; k0 += 32) {
    gload_lds16(gA + k0, ldsA + ldsw);
    if (BM == 128) gload_lds16(gA + (size_t)64 * KD + k0, ldsA + 2048 + ldsw);
    gload_lds16(gB + k0, ldsB + ldsw);
    gload_lds16(gB + (size_t)64 * KD + k0, ldsB + 2048 + ldsw);
    __syncthreads();
    bf16x8 a[MI], b[NI];
    #pragma unroll
    for (int i = 0; i < MI; i++)
      a[i] = *(const bf16x8*)(ldsA + (wm * 64 + i * 16 + lr) * 32 + lg * 8);
    #pragma unroll
    for (int j = 0; j < NI; j++)
      b[j] = *(const bf16x8*)(ldsB + (wn * NI * 16 + j * 16 + lr) * 32 + lg * 8);
    #pragma unroll
    for (int i = 0; i < MI; i++)
      #pragma unroll
      for (int j = 0; j < NI; j++)
        acc[i][j] = mfma16(a[i], b[j], acc[i][j]);
    __syncthreads();
  }
}

// ---------------- fused QKV GEMM: N=1536 -> q/k/v buffers ---------------------
__global__ __launch_bounds__(256) void gemm_qkv_kernel(const u16* __restrict__ A,
                                                       const u16* __restrict__ Wt,
                                                       const float* __restrict__ bq,
                                                       const float* __restrict__ bk,
                                                       const float* __restrict__ bv,
                                                       u16* __restrict__ q,
                                                       u16* __restrict__ k,
                                                       u16* __restrict__ v) {
  __shared__ u16 lds[8192];
  f32x4 acc[4][4] = {};
  gemm_core<128, 512>(A, Wt, lds, acc);
  const int lane = threadIdx.x & 63, w = threadIdx.x >> 6;
  const int lr = lane & 15, lg = lane >> 4;
  const int wm = w >> 1, wn = w & 1;
  const int r0 = blockIdx.x * 128, c0 = blockIdx.y * 128;
  #pragma unroll
  for (int j = 0; j < 4; j++) {
    int col = c0 + wn * 64 + j * 16 + lr;
    int sel = col >> 9, cc = col & 511;
    u16* outp = (sel == 0) ? q : (sel == 1) ? k : v;
    const float* bp = (sel == 0) ? bq : (sel == 1) ? bk : bv;
    float bias = bp[cc];
    #pragma unroll
    for (int i = 0; i < 4; i++) {
      int rbase = r0 + wm * 64 + i * 16 + lg * 4;
      #pragma unroll
      for (int r = 0; r < 4; r++)
        outp[(size_t)(rbase + r) * 512 + cc] = f2bf(acc[i][j][r] + bias);
    }
  }
}

// ---------------- FF1 GEMM: relu(h @ W1 + b1), N=2048 ------------------------
__global__ __launch_bounds__(256) void gemm_ff1_kernel(const u16* __restrict__ A,
                                                       const u16* __restrict__ Wt,
                                                       const float* __restrict__ bias,
                                                       u16* __restrict__ out) {
  __shared__ u16 lds[8192];
  f32x4 acc[4][4] = {};
  gemm_core<128, 512>(A, Wt, lds, acc);
  const int lane = threadIdx.x & 63, w = threadIdx.x >> 6;
  const int lr = lane & 15, lg = lane >> 4;
  const int wm = w >> 1, wn = w & 1;
  const int r0 = blockIdx.x * 128, c0 = blockIdx.y * 128;
  #pragma unroll
  for (int j = 0; j < 4; j++) {
    int col = c0 + wn * 64 + j * 16 + lr;
    float bv = bias[col];
    #pragma unroll
    for (int i = 0; i < 4; i++) {
      int rbase = r0 + wm * 64 + i * 16 + lg * 4;
      #pragma unroll
      for (int r = 0; r < 4; r++)
        out[(size_t)(rbase + r) * F + col] = f2bf(fmaxf(acc[i][j][r] + bv, 0.f));
    }
  }
}

// ---------------- residual GEMM: hf += A@W + b (N=512), BM=64 -----------------
template <int KD>
__global__ __launch_bounds__(256) void gemm_resid_kernel(const u16* __restrict__ A,
                                                         const u16* __restrict__ Wt,
                                                         const float* __restrict__ bias,
                                                         float* __restrict__ hf,
                                                         u16* __restrict__ hb) {
  __shared__ u16 lds[6144];
  f32x4 acc[4][4] = {};
  gemm_core<64, KD>(A, Wt, lds, acc);
  const int lane = threadIdx.x & 63, w = threadIdx.x >> 6;
  const int lr = lane & 15, lg = lane >> 4;
  const int wn = w;  // 1x4 wave grid
  const int r0 = blockIdx.x * 64, c0 = blockIdx.y * 128;
  #pragma unroll
  for (int j = 0; j < 2; j++) {
    int col = c0 + wn * 32 + j * 16 + lr;
    float bv = bias[col];
    #pragma unroll
    for (int i = 0; i < 4; i++) {
      int rbase = r0 + i * 16 + lg * 4;
      #pragma unroll
      for (int r = 0; r < 4; r++) {
        size_t idx = (size_t)(rbase + r) * D + col;
        float v = hf[idx] + acc[i][j][r] + bv;
        hf[idx] = v;
        hb[idx] = f2bf(v);
      }
    }
  }
}

// ---------------- V transpose: [B*S][HK] -> [B*H][64][S] ----------------------
__global__ __launch_bounds__(256) void vtrans_kernel(const u16* __restrict__ v,
                                                     u16* __restrict__ vt) {
  __shared__ u16 tile[64][65];
  int bh = blockIdx.x, b = bh >> 3, h = bh & 7;
  int s0 = blockIdx.y * 64;
  int t = threadIdx.x;
  union V16 { uint4 v4[2]; u16 e[16]; };
  {
    int sl = t >> 2, cc = (t & 3) * 16;
    const u16* src = v + (size_t)(b * S + s0 + sl) * HK + h * 64 + cc;
    V16 tv;
    tv.v4[0] = *(const uint4*)src;
    tv.v4[1] = *(const uint4*)(src + 8);
    #pragma unroll
    for (int i = 0; i < 16; i++) tile[sl][cc + i] = tv.e[i];
  }
  __syncthreads();
  {
    int kd = t >> 2, sc = (t & 3) * 16;
    V16 tv;
    #pragma unroll
    for (int i = 0; i < 16; i++) tv.e[i] = tile[sc + i][kd];
    u16* dst = vt + ((size_t)bh * 64 + kd) * S + s0 + sc;
    *(uint4*)dst = tv.v4[0];
    *(uint4*)(dst + 8) = tv.v4[1];
  }
}

// ---------------- flash attention: 32x32 swapped-operand structure ------------
// Each wave owns one 32-row q-tile. S^T = mfma32(K, Q): lane q = lane&31,
// 16 kv values in regs (kv = (r&3)+8*(r>>2)+4*hi). Softmax = in-lane tree +
// one shfl_xor(32). PV swapped too: O^T = mfma32(V^T, P^T) keeps q = lane&31.
// Causal balance: block y bundles q-tiles {2y, 2y+1, 62-2y, 63-2y} (equal work).
__global__ __launch_bounds__(256) void attn32_kernel(const u16* __restrict__ q,
                                                     const u16* __restrict__ k,
                                                     const u16* __restrict__ vt,
                                                     u16* __restrict__ o) {
  int bh = blockIdx.x, b = bh >> 3, h = bh & 7;
  int w = threadIdx.x >> 6, lane = threadIdx.x & 63;
  int y = blockIdx.y;
  int tile = (w == 0) ? 2 * y : (w == 1) ? 2 * y + 1 : (w == 2) ? 62 - 2 * y : 63 - 2 * y;
  int q0 = tile * 32;
  int ql = lane & 31, hi = lane >> 5;
  int qa = q0 + ql;  // absolute q row for this lane

  // Q B-frags (persistent): B[k][q]=Q[q][k]: col=lane&31=q, k=16*kc+8*hi+j
  const u16* qrow = q + (size_t)(b * S + qa) * HK + h * 64;
  bf16x8 qf[4];
  #pragma unroll
  for (int kc = 0; kc < 4; kc++) qf[kc] = *(const bf16x8*)(qrow + kc * 16 + hi * 8);

  const u16* kbase = k + (size_t)(b * S) * HK + h * 64;
  const u16* vbase = vt + (size_t)bh * 64 * S;

  f32x16 oacc[2] = {};
  float mrun = -3.0e38f, lrun = 0.f;
  int nsteps = tile + 1;

  for (int st_i = 0; st_i < nsteps; st_i++) {
    int kv0 = st_i * 32;
    // K A-frags: A[kv][k]: row=lane&31=kv-local, k=16*kc+8*hi+j
    const u16* kr = kbase + (size_t)(kv0 + ql) * HK;
    bf16x8 kf[4];
    #pragma unroll
    for (int kc = 0; kc < 4; kc++) kf[kc] = *(const bf16x8*)(kr + kc * 16 + hi * 8);
    // V^T A-frags: A[d][kv]: row=lane&31=d-local(+32*dt), k=kv-local16=8*hi+j
    bf16x8 vf[2][2];
    #pragma unroll
    for (int km = 0; km < 2; km++)
      #pragma unroll
      for (int dt = 0; dt < 2; dt++)
        vf[km][dt] = *(const bf16x8*)(vbase + (size_t)(dt * 32 + ql) * S + kv0 + km * 16 + hi * 8);

    f32x16 sacc = {};
    #pragma unroll
    for (int kc = 0; kc < 4; kc++) sacc = mfma32(kf[kc], qf[kc], sacc);

    // scale + causal mask; kv_abs = kv0 + (r&3)+8*(r>>2)+4*hi
    float p[16];
    #pragma unroll
    for (int r = 0; r < 16; r++) {
      int kva = kv0 + (r & 3) + 8 * (r >> 2) + 4 * hi;
      float sv = sacc[r] * 0.125f;
      p[r] = (kva > qa) ? -1e30f : sv;
    }
    // row max: in-lane tree + cross-half swap
    float mx = fmaxf(fmaxf(fmaxf(p[0], p[1]), fmaxf(p[2], p[3])),
                     fmaxf(fmaxf(p[4], p[5]), fmaxf(p[6], p[7])));
    float mx2 = fmaxf(fmaxf(fmaxf(p[8], p[9]), fmaxf(p[10], p[11])),
                      fmaxf(fmaxf(p[12], p[13]), fmaxf(p[14], p[15])));
    mx = fmaxf(mx, mx2);
    mx = fmaxf(mx, __shfl_xor(mx, 32));
    float mnew = fmaxf(mrun, mx);
    float corr = __expf(mrun - mnew);
    mrun = mnew;
    #pragma unroll
    for (int r = 0; r < 16; r++) p[r] = __expf(p[r] - mnew);
    float ps = ((p[0] + p[1]) + (p[2] + p[3])) + ((p[4] + p[5]) + (p[6] + p[7]))
             + ((p[8] + p[9]) + (p[10] + p[11])) + ((p[12] + p[13]) + (p[14] + p[15]));
    ps += __shfl_xor(ps, 32);
    lrun = lrun * corr + ps;
    #pragma unroll
    for (int dt = 0; dt < 2; dt++)
      #pragma unroll
      for (int r = 0; r < 16; r++) oacc[dt][r] *= corr;

    // P^T repack to B-frag (k=kv): lane hi needs m=8*hi+j of each 16-chunk.
    // own m = 4*hi + 8*a + (r&3), a=(r>>2)&1; partner (lane^32) supplies the rest.
    #pragma unroll
    for (int km = 0; km < 2; km++) {
      int base = 8 * km;
      u32 a0_01 = pk2(p[base + 0], p[base + 1]);
      u32 a0_23 = pk2(p[base + 2], p[base + 3]);
      u32 a1_01 = pk2(p[base + 4], p[base + 5]);
      u32 a1_23 = pk2(p[base + 6], p[base + 7]);
      u32 send1 = hi ? a0_01 : a1_01;
      u32 send2 = hi ? a0_23 : a1_23;
      u32 recv1 = __shfl_xor(send1, 32);
      u32 recv2 = __shfl_xor(send2, 32);
      union { u32 w[4]; bf16x8 v; } pf;
      if (hi == 0) { pf.w[0] = a0_01; pf.w[1] = a0_23; pf.w[2] = recv1; pf.w[3] = recv2; }
      else         { pf.w[0] = recv1; pf.w[1] = recv2; pf.w[2] = a1_01; pf.w[3] = a1_23; }
      oacc[0] = mfma32(vf[km][0], pf.v, oacc[0]);
      oacc[1] = mfma32(vf[km][1], pf.v, oacc[1]);
    }
  }

  // O^T: lane q = lane&31; d = dt*32 + 8*rq + 4*hi + (r&3)
  float inv = 1.0f / lrun;
  u16* orow = o + (size_t)(b * S + qa) * HK + h * 64;
  #pragma unroll
  for (int dt = 0; dt < 2; dt++)
    #pragma unroll
    for (int rq = 0; rq < 4; rq++) {
      int d0 = dt * 32 + 8 * rq + 4 * hi;
      uint2 val;
      val.x = pk2(oacc[dt][4 * rq + 0] * inv, oacc[dt][4 * rq + 1] * inv);
      val.y = pk2(oacc[dt][4 * rq + 2] * inv, oacc[dt][4 * rq + 3] * inv);
      *(uint2*)(orow + d0) = val;
    }
}

extern "C" void kernel_launch(void* const* d_in, const int* in_sizes, int n_in,
                              void* d_out, int out_size, void* d_ws, size_t ws_size,
                              hipStream_t stream) {
  const int* x = (const int*)d_in[0];
  const float* emb = (const float*)d_in[1];
  const float* pos = (const float*)d_in[2];
  const float* Wq = (const float*)d_in[3];
  const float* bq = (const float*)d_in[4];
  const float* Wk = (const float*)d_in[5];
  const float* bk = (const float*)d_in[6];
  const float* Wv = (const float*)d_in[7];
  const float* bv = (const float*)d_in[8];
  const float* Wo = (const float*)d_in[9];
  const float* bo = (const float*)d_in[10];
  const float* W1 = (const float*)d_in[11];
  const float* b1 = (const float*)d_in[12];
  const float* W2 = (const float*)d_in[13];
  const float* b2 = (const float*)d_in[14];
  float* hf = (float*)d_out;

  char* p = (char*)d_ws;
  const size_t SZ_MD = (size_t)M * D * 2;  // 4MB
  u16* h_bf = (u16*)p;  p += SZ_MD;
  u16* q_bf = (u16*)p;  p += SZ_MD;
  u16* k_bf = (u16*)p;  p += SZ_MD;
  u16* v_bf = (u16*)p;  p += SZ_MD;
  u16* vt_bf = (u16*)p; p += SZ_MD;
  u16* o_bf = (u16*)p;  p += SZ_MD;
  u16* ff_bf = (u16*)p; p += (size_t)M * F * 2;
  u16* WqkvT = (u16*)p; p += (size_t)L * D * (3 * HK) * 2;  // [L][1536][512]
  u16* WoT = (u16*)p;   p += (size_t)L * HK * D * 2;
  u16* W1T = (u16*)p;   p += (size_t)L * D * F * 2;
  u16* W2T = (u16*)p;   p += (size_t)L * F * D * 2;

  dim3 tb(32, 8);
  const int QKV_L = 3 * HK * D;  // per-layer stride of fused qkv weights
  wtrans_kernel<<<dim3(D / 32, HK / 32, L), tb, 0, stream>>>(Wq, WqkvT, D, HK, QKV_L);
  wtrans_kernel<<<dim3(D / 32, HK / 32, L), tb, 0, stream>>>(Wk, WqkvT + HK * D, D, HK, QKV_L);
  wtrans_kernel<<<dim3(D / 32, HK / 32, L), tb, 0, stream>>>(Wv, WqkvT + 2 * HK * D, D, HK, QKV_L);
  wtrans_kernel<<<dim3(HK / 32, D / 32, L), tb, 0, stream>>>(Wo, WoT, HK, D, HK * D);
  wtrans_kernel<<<dim3(D / 32, F / 32, L), tb, 0, stream>>>(W1, W1T, D, F, D * F);
  wtrans_kernel<<<dim3(F / 32, D / 32, L), tb, 0, stream>>>(W2, W2T, F, D, F * D);

  embed_kernel<<<(M * D / 4) / 256, 256, 0, stream>>>(x, emb, pos, hf, h_bf);

  for (int l = 0; l < L; ++l) {
    gemm_qkv_kernel<<<dim3(M / 128, (3 * HK) / 128), 256, 0, stream>>>(
        h_bf, WqkvT + (size_t)l * QKV_L, bq + l * HK, bk + l * HK, bv + l * HK,
        q_bf, k_bf, v_bf);
    vtrans_kernel<<<dim3(B * H, S / 64), 256, 0, stream>>>(v_bf, vt_bf);
    attn32_kernel<<<dim3(B * H, 16), 256, 0, stream>>>(q_bf, k_bf, vt_bf, o_bf);
    gemm_resid_kernel<512><<<dim3(M / 64, D / 128), 256, 0, stream>>>(
        o_bf, WoT + (size_t)l * HK * D, bo + l * D, hf, h_bf);
    gemm_ff1_kernel<<<dim3(M / 128, F / 128), 256, 0, stream>>>(
        h_bf, W1T + (size_t)l * D * F, b1 + l * F, ff_bf);
    gemm_resid_kernel<2048><<<dim3(M / 64, D / 128), 256, 0, stream>>>(
        ff_bf, W2T + (size_t)l * F * D, b2 + l * D, hf, h_bf);
  }
}

// Round 5
// 690.953 us; speedup vs baseline: 2.2713x; 1.2318x over previous
//
#include <hip/hip_runtime.h>

typedef __bf16 bf16x8 __attribute__((ext_vector_type(8)));
typedef float f32x4 __attribute__((ext_vector_type(4)));
typedef float f32x16 __attribute__((ext_vector_type(16)));
typedef unsigned short u16;
typedef unsigned int u32;

static constexpr int B = 2, S = 2048, D = 512, H = 8, HD = 64, F = 2048, L = 4, HK = 512, M = 4096;

__device__ __forceinline__ u16 f2bf(float f) {
  u32 u = __float_as_uint(f);
  u = (u + 0x7fffu + ((u >> 16) & 1u)) >> 16;
  return (u16)u;
}

__device__ __forceinline__ u32 pk2(float lo, float hi) {
  return (u32)f2bf(lo) | ((u32)f2bf(hi) << 16);
}

__device__ __forceinline__ f32x4 mfma16(bf16x8 a, bf16x8 b, f32x4 c) {
  return __builtin_amdgcn_mfma_f32_16x16x32_bf16(a, b, c, 0, 0, 0);
}

__device__ __forceinline__ f32x16 mfma32(bf16x8 a, bf16x8 b, f32x16 c) {
  return __builtin_amdgcn_mfma_f32_32x32x16_bf16(a, b, c, 0, 0, 0);
}

__device__ __forceinline__ void gload_lds16(const u16* g, u16* l) {
  __builtin_amdgcn_global_load_lds((const __attribute__((address_space(1))) void*)g,
                                   (__attribute__((address_space(3))) void*)l, 16, 0, 0);
}

// ---------------- weight transpose: fp32 [R][C] -> bf16 [C][R] ----------------
__global__ __launch_bounds__(256) void wtrans_kernel(const float* __restrict__ in,
                                                     u16* __restrict__ out,
                                                     int R, int C, int ostride) {
  __shared__ float tile[32][33];
  in += (size_t)blockIdx.z * R * C;
  out += (size_t)blockIdx.z * ostride;
  int r0 = blockIdx.x * 32, c0 = blockIdx.y * 32;
  int tx = threadIdx.x, ty = threadIdx.y;  // (32,8)
  #pragma unroll
  for (int i = ty; i < 32; i += 8)
    tile[i][tx] = in[(size_t)(r0 + i) * C + c0 + tx];
  __syncthreads();
  #pragma unroll
  for (int i = ty; i < 32; i += 8)
    out[(size_t)(c0 + i) * R + r0 + tx] = f2bf(tile[tx][i]);
}

// ---------------- embedding: h = emb[x] + pos (fp32 master + bf16 shadow) -----
__global__ __launch_bounds__(256) void embed_kernel(const int* __restrict__ x,
                                                    const float* __restrict__ emb,
                                                    const float* __restrict__ pos,
                                                    float* __restrict__ hf,
                                                    u16* __restrict__ hb) {
  int idx = blockIdx.x * 256 + threadIdx.x;  // over M * D/4
  int dc = idx & 127;                        // D/4 = 128
  int bs = idx >> 7;
  int s = bs & (S - 1);
  int tok = x[bs];
  float4 e = ((const float4*)(emb + (size_t)tok * D))[dc];
  float4 p = ((const float4*)(pos + (size_t)s * D))[dc];
  float4 v;
  v.x = e.x + p.x; v.y = e.y + p.y; v.z = e.z + p.z; v.w = e.w + p.w;
  ((float4*)hf)[idx] = v;
  ushort4 u;
  u.x = f2bf(v.x); u.y = f2bf(v.y); u.z = f2bf(v.z); u.w = f2bf(v.w);
  ((ushort4*)hb)[idx] = u;
}

// ---------------- m97-style GEMM core: BM x 128 tile, BK=32, global_load_lds --
template <int BM, int KD>
__device__ __forceinline__ void gemm_core(const u16* __restrict__ A,
                                          const u16* __restrict__ Wt,
                                          u16* lds, f32x4 (&acc)[4][4]) {
  constexpr int WN = (BM == 128) ? 2 : 4;  // waves along N
  constexpr int NI = 8 / WN;               // 16-col frags per wave
  constexpr int MI = 4;                    // 16-row frags per wave
  const int t = threadIdx.x;
  const int lane = t & 63, w = t >> 6;
  const int lr = lane & 15, lg = lane >> 4;
  const int wm = w / WN, wn = w % WN;
  const int r0 = blockIdx.x * BM, c0 = blockIdx.y * 128;
  u16* ldsA = lds;                 // [BM][32]
  u16* ldsB = lds + BM * 32;       // [128][32]
  const int srow = t >> 2, scol = (t & 3) * 8;
  const u16* gA = A + (size_t)(r0 + srow) * KD + scol;
  const u16* gB = Wt + (size_t)(c0 + srow) * KD + scol;
  const int ldsw = w * 512;        // 1 KB per wave (elements)

  for (int k0 = 0; k0 < KD; k0 += 32) {
    gload_lds16(gA + k0, ldsA + ldsw);
    if (BM == 128) gload_lds16(gA + (size_t)64 * KD + k0, ldsA + 2048 + ldsw);
    gload_lds16(gB + k0, ldsB + ldsw);
    gload_lds16(gB + (size_t)64 * KD + k0, ldsB + 2048 + ldsw);
    __syncthreads();
    bf16x8 a[MI], b[NI];
    #pragma unroll
    for (int i = 0; i < MI; i++)
      a[i] = *(const bf16x8*)(ldsA + (wm * 64 + i * 16 + lr) * 32 + lg * 8);
    #pragma unroll
    for (int j = 0; j < NI; j++)
      b[j] = *(const bf16x8*)(ldsB + (wn * NI * 16 + j * 16 + lr) * 32 + lg * 8);
    #pragma unroll
    for (int i = 0; i < MI; i++)
      #pragma unroll
      for (int j = 0; j < NI; j++)
        acc[i][j] = mfma16(a[i], b[j], acc[i][j]);
    __syncthreads();
  }
}

// ---------------- fused QKV GEMM: N=1536 -> q/k/v buffers ---------------------
__global__ __launch_bounds__(256) void gemm_qkv_kernel(const u16* __restrict__ A,
                                                       const u16* __restrict__ Wt,
                                                       const float* __restrict__ bq,
                                                       const float* __restrict__ bk,
                                                       const float* __restrict__ bv,
                                                       u16* __restrict__ q,
                                                       u16* __restrict__ k,
                                                       u16* __restrict__ v) {
  __shared__ u16 lds[8192];
  f32x4 acc[4][4] = {};
  gemm_core<128, 512>(A, Wt, lds, acc);
  const int lane = threadIdx.x & 63, w = threadIdx.x >> 6;
  const int lr = lane & 15, lg = lane >> 4;
  const int wm = w >> 1, wn = w & 1;
  const int r0 = blockIdx.x * 128, c0 = blockIdx.y * 128;
  #pragma unroll
  for (int j = 0; j < 4; j++) {
    int col = c0 + wn * 64 + j * 16 + lr;
    int sel = col >> 9, cc = col & 511;
    u16* outp = (sel == 0) ? q : (sel == 1) ? k : v;
    const float* bp = (sel == 0) ? bq : (sel == 1) ? bk : bv;
    float bias = bp[cc];
    #pragma unroll
    for (int i = 0; i < 4; i++) {
      int rbase = r0 + wm * 64 + i * 16 + lg * 4;
      #pragma unroll
      for (int r = 0; r < 4; r++)
        outp[(size_t)(rbase + r) * 512 + cc] = f2bf(acc[i][j][r] + bias);
    }
  }
}

// ---------------- FF1 GEMM: relu(h @ W1 + b1), N=2048 ------------------------
__global__ __launch_bounds__(256) void gemm_ff1_kernel(const u16* __restrict__ A,
                                                       const u16* __restrict__ Wt,
                                                       const float* __restrict__ bias,
                                                       u16* __restrict__ out) {
  __shared__ u16 lds[8192];
  f32x4 acc[4][4] = {};
  gemm_core<128, 512>(A, Wt, lds, acc);
  const int lane = threadIdx.x & 63, w = threadIdx.x >> 6;
  const int lr = lane & 15, lg = lane >> 4;
  const int wm = w >> 1, wn = w & 1;
  const int r0 = blockIdx.x * 128, c0 = blockIdx.y * 128;
  #pragma unroll
  for (int j = 0; j < 4; j++) {
    int col = c0 + wn * 64 + j * 16 + lr;
    float bv = bias[col];
    #pragma unroll
    for (int i = 0; i < 4; i++) {
      int rbase = r0 + wm * 64 + i * 16 + lg * 4;
      #pragma unroll
      for (int r = 0; r < 4; r++)
        out[(size_t)(rbase + r) * F + col] = f2bf(fmaxf(acc[i][j][r] + bv, 0.f));
    }
  }
}

// ---------------- residual GEMM: hf += A@W + b (N=512), BM=64 -----------------
template <int KD>
__global__ __launch_bounds__(256) void gemm_resid_kernel(const u16* __restrict__ A,
                                                         const u16* __restrict__ Wt,
                                                         const float* __restrict__ bias,
                                                         float* __restrict__ hf,
                                                         u16* __restrict__ hb) {
  __shared__ u16 lds[6144];
  f32x4 acc[4][4] = {};
  gemm_core<64, KD>(A, Wt, lds, acc);
  const int lane = threadIdx.x & 63, w = threadIdx.x >> 6;
  const int lr = lane & 15, lg = lane >> 4;
  const int wn = w;  // 1x4 wave grid
  const int r0 = blockIdx.x * 64, c0 = blockIdx.y * 128;
  #pragma unroll
  for (int j = 0; j < 2; j++) {
    int col = c0 + wn * 32 + j * 16 + lr;
    float bv = bias[col];
    #pragma unroll
    for (int i = 0; i < 4; i++) {
      int rbase = r0 + i * 16 + lg * 4;
      #pragma unroll
      for (int r = 0; r < 4; r++) {
        size_t idx = (size_t)(rbase + r) * D + col;
        float v = hf[idx] + acc[i][j][r] + bv;
        hf[idx] = v;
        hb[idx] = f2bf(v);
      }
    }
  }
}

// ---------------- V transpose: [B*S][HK] -> [B*H][64][S] ----------------------
__global__ __launch_bounds__(256) void vtrans_kernel(const u16* __restrict__ v,
                                                     u16* __restrict__ vt) {
  __shared__ u16 tile[64][65];
  int bh = blockIdx.x, b = bh >> 3, h = bh & 7;
  int s0 = blockIdx.y * 64;
  int t = threadIdx.x;
  union V16 { uint4 v4[2]; u16 e[16]; };
  {
    int sl = t >> 2, cc = (t & 3) * 16;
    const u16* src = v + (size_t)(b * S + s0 + sl) * HK + h * 64 + cc;
    V16 tv;
    tv.v4[0] = *(const uint4*)src;
    tv.v4[1] = *(const uint4*)(src + 8);
    #pragma unroll
    for (int i = 0; i < 16; i++) tile[sl][cc + i] = tv.e[i];
  }
  __syncthreads();
  {
    int kd = t >> 2, sc = (t & 3) * 16;
    V16 tv;
    #pragma unroll
    for (int i = 0; i < 16; i++) tv.e[i] = tile[sc + i][kd];
    u16* dst = vt + ((size_t)bh * 64 + kd) * S + s0 + sc;
    *(uint4*)dst = tv.v4[0];
    *(uint4*)(dst + 8) = tv.v4[1];
  }
}

// ---------------- flash attention v2: split-KV, 1 block per (bh, 32-row tile) -
// Swapped 32x32 structure (lane q = lane&31). Block's 4 waves split kv-steps
// by stride-4 interleave; each keeps private (m,l,oacc); LDS combine merges.
__device__ __forceinline__ void load_kv(const u16* kbase, const u16* vbase,
                                        int kv0, int ql, int hi,
                                        bf16x8 (&kf)[4], bf16x8 (&vf)[4]) {
  const u16* kr = kbase + (size_t)(kv0 + ql) * HK;
  #pragma unroll
  for (int kc = 0; kc < 4; kc++) kf[kc] = *(const bf16x8*)(kr + kc * 16 + hi * 8);
  #pragma unroll
  for (int km = 0; km < 2; km++)
    #pragma unroll
    for (int dt = 0; dt < 2; dt++)
      vf[km * 2 + dt] = *(const bf16x8*)(vbase + (size_t)(dt * 32 + ql) * S + kv0 + km * 16 + hi * 8);
}

__global__ __launch_bounds__(256) void attn32_kernel(const u16* __restrict__ q,
                                                     const u16* __restrict__ k,
                                                     const u16* __restrict__ vt,
                                                     u16* __restrict__ o) {
  __shared__ float lds_o[4][64][32];  // [wave][d][q]
  __shared__ float lds_m[4][32];
  __shared__ float lds_l[4][32];
  int bh = blockIdx.x, b = bh >> 3, h = bh & 7;
  int w = threadIdx.x >> 6, lane = threadIdx.x & 63;
  int tile = 63 - blockIdx.y;  // big-work blocks first
  int q0 = tile * 32;
  int ql = lane & 31, hi = lane >> 5;
  int qa = q0 + ql;

  const u16* qrow = q + (size_t)(b * S + qa) * HK + h * 64;
  bf16x8 qf[4];
  #pragma unroll
  for (int kc = 0; kc < 4; kc++) qf[kc] = *(const bf16x8*)(qrow + kc * 16 + hi * 8);

  const u16* kbase = k + (size_t)(b * S) * HK + h * 64;
  const u16* vbase = vt + (size_t)bh * 64 * S;

  f32x16 oacc[2] = {};
  float mrun = -3.0e38f, lrun = 0.f;
  int cnt = (w <= tile) ? ((tile - w) >> 2) + 1 : 0;
  int s = w;

  bf16x8 kf[4], vf[4], kn[4], vn[4];
  if (cnt > 0) load_kv(kbase, vbase, s * 32, ql, hi, kf, vf);

  for (int i = 0; i < cnt; i++) {
    if (i + 1 < cnt) load_kv(kbase, vbase, (s + 4) * 32, ql, hi, kn, vn);
    int kv0 = s * 32;
    f32x16 sacc = {};
    #pragma unroll
    for (int kc = 0; kc < 4; kc++) sacc = mfma32(kf[kc], qf[kc], sacc);

    float p[16];
    if (s == tile) {  // diagonal step: causal mask needed
      #pragma unroll
      for (int r = 0; r < 16; r++) {
        int kva = kv0 + (r & 3) + 8 * (r >> 2) + 4 * hi;
        p[r] = (kva > qa) ? -1e30f : sacc[r] * 0.125f;
      }
    } else {
      #pragma unroll
      for (int r = 0; r < 16; r++) p[r] = sacc[r] * 0.125f;
    }

    float mx = fmaxf(fmaxf(fmaxf(p[0], p[1]), fmaxf(p[2], p[3])),
                     fmaxf(fmaxf(p[4], p[5]), fmaxf(p[6], p[7])));
    float mx2 = fmaxf(fmaxf(fmaxf(p[8], p[9]), fmaxf(p[10], p[11])),
                      fmaxf(fmaxf(p[12], p[13]), fmaxf(p[14], p[15])));
    mx = fmaxf(mx, mx2);
    mx = fmaxf(mx, __shfl_xor(mx, 32));
    float mnew = fmaxf(mrun, mx);
    float corr = __expf(mrun - mnew);
    mrun = mnew;
    #pragma unroll
    for (int r = 0; r < 16; r++) p[r] = __expf(p[r] - mnew);
    float ps = ((p[0] + p[1]) + (p[2] + p[3])) + ((p[4] + p[5]) + (p[6] + p[7]))
             + ((p[8] + p[9]) + (p[10] + p[11])) + ((p[12] + p[13]) + (p[14] + p[15]));
    ps += __shfl_xor(ps, 32);
    lrun = lrun * corr + ps;
    #pragma unroll
    for (int dt = 0; dt < 2; dt++)
      #pragma unroll
      for (int r = 0; r < 16; r++) oacc[dt][r] *= corr;

    #pragma unroll
    for (int km = 0; km < 2; km++) {
      int base = 8 * km;
      u32 a0_01 = pk2(p[base + 0], p[base + 1]);
      u32 a0_23 = pk2(p[base + 2], p[base + 3]);
      u32 a1_01 = pk2(p[base + 4], p[base + 5]);
      u32 a1_23 = pk2(p[base + 6], p[base + 7]);
      u32 send1 = hi ? a0_01 : a1_01;
      u32 send2 = hi ? a0_23 : a1_23;
      u32 recv1 = __shfl_xor(send1, 32);
      u32 recv2 = __shfl_xor(send2, 32);
      union { u32 wd[4]; bf16x8 v; } pf;
      if (hi == 0) { pf.wd[0] = a0_01; pf.wd[1] = a0_23; pf.wd[2] = recv1; pf.wd[3] = recv2; }
      else         { pf.wd[0] = recv1; pf.wd[1] = recv2; pf.wd[2] = a1_01; pf.wd[3] = a1_23; }
      oacc[0] = mfma32(vf[km * 2 + 0], pf.v, oacc[0]);
      oacc[1] = mfma32(vf[km * 2 + 1], pf.v, oacc[1]);
    }
    #pragma unroll
    for (int j = 0; j < 4; j++) { kf[j] = kn[j]; vf[j] = vn[j]; }
    s += 4;
  }

  // write partials: m,l (hi==0 lanes), oacc -> lds_o[w][d][q]
  if (hi == 0) { lds_m[w][ql] = mrun; lds_l[w][ql] = lrun; }
  #pragma unroll
  for (int dt = 0; dt < 2; dt++)
    #pragma unroll
    for (int r = 0; r < 16; r++) {
      int d = dt * 32 + (r & 3) + 8 * (r >> 2) + 4 * hi;
      lds_o[w][d][ql] = oacc[dt][r];
    }
  __syncthreads();

  // combine: all waves read 4 partials for q=ql; wave w covers d in [16w,16w+16)
  float m0 = lds_m[0][ql], m1 = lds_m[1][ql], m2 = lds_m[2][ql], m3 = lds_m[3][ql];
  float Mx = fmaxf(fmaxf(m0, m1), fmaxf(m2, m3));
  float s0 = __expf(m0 - Mx), s1 = __expf(m1 - Mx), s2 = __expf(m2 - Mx), s3 = __expf(m3 - Mx);
  float Ls = lds_l[0][ql] * s0 + lds_l[1][ql] * s1 + lds_l[2][ql] * s2 + lds_l[3][ql] * s3;
  float inv = 1.0f / Ls;
  int dbase = w * 16 + hi * 8;
  union { uint4 u4; u16 e[8]; } outv;
  #pragma unroll
  for (int j = 0; j < 8; j++) {
    int d = dbase + j;
    float v = (lds_o[0][d][ql] * s0 + lds_o[1][d][ql] * s1 +
               lds_o[2][d][ql] * s2 + lds_o[3][d][ql] * s3) * inv;
    outv.e[j] = f2bf(v);
  }
  *(uint4*)(o + (size_t)(b * S + qa) * HK + h * 64 + dbase) = outv.u4;
}

extern "C" void kernel_launch(void* const* d_in, const int* in_sizes, int n_in,
                              void* d_out, int out_size, void* d_ws, size_t ws_size,
                              hipStream_t stream) {
  const int* x = (const int*)d_in[0];
  const float* emb = (const float*)d_in[1];
  const float* pos = (const float*)d_in[2];
  const float* Wq = (const float*)d_in[3];
  const float* bq = (const float*)d_in[4];
  const float* Wk = (const float*)d_in[5];
  const float* bk = (const float*)d_in[6];
  const float* Wv = (const float*)d_in[7];
  const float* bv = (const float*)d_in[8];
  const float* Wo = (const float*)d_in[9];
  const float* bo = (const float*)d_in[10];
  const float* W1 = (const float*)d_in[11];
  const float* b1 = (const float*)d_in[12];
  const float* W2 = (const float*)d_in[13];
  const float* b2 = (const float*)d_in[14];
  float* hf = (float*)d_out;

  char* p = (char*)d_ws;
  const size_t SZ_MD = (size_t)M * D * 2;  // 4MB
  u16* h_bf = (u16*)p;  p += SZ_MD;
  u16* q_bf = (u16*)p;  p += SZ_MD;
  u16* k_bf = (u16*)p;  p += SZ_MD;
  u16* v_bf = (u16*)p;  p += SZ_MD;
  u16* vt_bf = (u16*)p; p += SZ_MD;
  u16* o_bf = (u16*)p;  p += SZ_MD;
  u16* ff_bf = (u16*)p; p += (size_t)M * F * 2;
  u16* WqkvT = (u16*)p; p += (size_t)L * D * (3 * HK) * 2;  // [L][1536][512]
  u16* WoT = (u16*)p;   p += (size_t)L * HK * D * 2;
  u16* W1T = (u16*)p;   p += (size_t)L * D * F * 2;
  u16* W2T = (u16*)p;   p += (size_t)L * F * D * 2;

  dim3 tb(32, 8);
  const int QKV_L = 3 * HK * D;  // per-layer stride of fused qkv weights
  wtrans_kernel<<<dim3(D / 32, HK / 32, L), tb, 0, stream>>>(Wq, WqkvT, D, HK, QKV_L);
  wtrans_kernel<<<dim3(D / 32, HK / 32, L), tb, 0, stream>>>(Wk, WqkvT + HK * D, D, HK, QKV_L);
  wtrans_kernel<<<dim3(D / 32, HK / 32, L), tb, 0, stream>>>(Wv, WqkvT + 2 * HK * D, D, HK, QKV_L);
  wtrans_kernel<<<dim3(HK / 32, D / 32, L), tb, 0, stream>>>(Wo, WoT, HK, D, HK * D);
  wtrans_kernel<<<dim3(D / 32, F / 32, L), tb, 0, stream>>>(W1, W1T, D, F, D * F);
  wtrans_kernel<<<dim3(F / 32, D / 32, L), tb, 0, stream>>>(W2, W2T, F, D, F * D);

  embed_kernel<<<(M * D / 4) / 256, 256, 0, stream>>>(x, emb, pos, hf, h_bf);

  for (int l = 0; l < L; ++l) {
    gemm_qkv_kernel<<<dim3(M / 128, (3 * HK) / 128), 256, 0, stream>>>(
        h_bf, WqkvT + (size_t)l * QKV_L, bq + l * HK, bk + l * HK, bv + l * HK,
        q_bf, k_bf, v_bf);
    vtrans_kernel<<<dim3(B * H, S / 64), 256, 0, stream>>>(v_bf, vt_bf);
    attn32_kernel<<<dim3(B * H, 64), 256, 0, stream>>>(q_bf, k_bf, vt_bf, o_bf);
    gemm_resid_kernel<512><<<dim3(M / 64, D / 128), 256, 0, stream>>>(
        o_bf, WoT + (size_t)l * HK * D, bo + l * D, hf, h_bf);
    gemm_ff1_kernel<<<dim3(M / 128, F / 128), 256, 0, stream>>>(
        h_bf, W1T + (size_t)l * D * F, b1 + l * F, ff_bf);
    gemm_resid_kernel<2048><<<dim3(M / 64, D / 128), 256, 0, stream>>>(
        ff_bf, W2T + (size_t)l * F * D, b2 + l * D, hf, h_bf);
  }
}

// Round 6
// 654.885 us; speedup vs baseline: 2.3964x; 1.0551x over previous
//
#include <hip/hip_runtime.h>

typedef __bf16 bf16x8 __attribute__((ext_vector_type(8)));
typedef float f32x4 __attribute__((ext_vector_type(4)));
typedef float f32x16 __attribute__((ext_vector_type(16)));
typedef unsigned short u16;
typedef unsigned int u32;

static constexpr int B = 2, S = 2048, D = 512, H = 8, HD = 64, F = 2048, L = 4, HK = 512, M = 4096;

__device__ __forceinline__ u16 f2bf(float f) {
  u32 u = __float_as_uint(f);
  u = (u + 0x7fffu + ((u >> 16) & 1u)) >> 16;
  return (u16)u;
}

// truncating pack: [hi.bf16 | lo.bf16] in one v_perm_b32
__device__ __forceinline__ u32 pk2t(float lo, float hi2) {
  return __builtin_amdgcn_perm(__float_as_uint(hi2), __float_as_uint(lo), 0x07060302u);
}

__device__ __forceinline__ f32x4 mfma16(bf16x8 a, bf16x8 b, f32x4 c) {
  return __builtin_amdgcn_mfma_f32_16x16x32_bf16(a, b, c, 0, 0, 0);
}

__device__ __forceinline__ f32x16 mfma32(bf16x8 a, bf16x8 b, f32x16 c) {
  return __builtin_amdgcn_mfma_f32_32x32x16_bf16(a, b, c, 0, 0, 0);
}

__device__ __forceinline__ void gload_lds16(const u16* g, u16* l) {
  __builtin_amdgcn_global_load_lds((const __attribute__((address_space(1))) void*)g,
                                   (__attribute__((address_space(3))) void*)l, 16, 0, 0);
}

// ---------------- weight transpose: fp32 [R][C] -> bf16 [C][R] ----------------
__global__ __launch_bounds__(256) void wtrans_kernel(const float* __restrict__ in,
                                                     u16* __restrict__ out,
                                                     int R, int C, int ostride) {
  __shared__ float tile[32][33];
  in += (size_t)blockIdx.z * R * C;
  out += (size_t)blockIdx.z * ostride;
  int r0 = blockIdx.x * 32, c0 = blockIdx.y * 32;
  int tx = threadIdx.x, ty = threadIdx.y;  // (32,8)
  #pragma unroll
  for (int i = ty; i < 32; i += 8)
    tile[i][tx] = in[(size_t)(r0 + i) * C + c0 + tx];
  __syncthreads();
  #pragma unroll
  for (int i = ty; i < 32; i += 8)
    out[(size_t)(c0 + i) * R + r0 + tx] = f2bf(tile[tx][i]);
}

// ---------------- embedding: h = emb[x] + pos (fp32 master + bf16 shadow) -----
__global__ __launch_bounds__(256) void embed_kernel(const int* __restrict__ x,
                                                    const float* __restrict__ emb,
                                                    const float* __restrict__ pos,
                                                    float* __restrict__ hf,
                                                    u16* __restrict__ hb) {
  int idx = blockIdx.x * 256 + threadIdx.x;  // over M * D/4
  int dc = idx & 127;                        // D/4 = 128
  int bs = idx >> 7;
  int s = bs & (S - 1);
  int tok = x[bs];
  float4 e = ((const float4*)(emb + (size_t)tok * D))[dc];
  float4 p = ((const float4*)(pos + (size_t)s * D))[dc];
  float4 v;
  v.x = e.x + p.x; v.y = e.y + p.y; v.z = e.z + p.z; v.w = e.w + p.w;
  ((float4*)hf)[idx] = v;
  ushort4 u;
  u.x = f2bf(v.x); u.y = f2bf(v.y); u.z = f2bf(v.z); u.w = f2bf(v.w);
  ((ushort4*)hb)[idx] = u;
}

// ---------------- GEMM core: BM x 128 tile, BK=64, swizzled LDS ---------------
// A: bf16 [M][KD] row-major; Wt: bf16 [N][KD] row-major (pre-transposed).
// LDS [row][64] with XOR-swizzle: granule g of row r holds global granule
// g^(r&7); staged via inverse-permuted GLOBAL source (linear LDS dest, rule 21).
template <int BM, int KD>
__device__ __forceinline__ void gemm_core(const u16* __restrict__ A,
                                          const u16* __restrict__ Wt,
                                          u16* lds, f32x4 (&acc)[4][4]) {
  constexpr int WN = (BM == 128) ? 2 : 4;  // waves along N
  constexpr int NI = 8 / WN;               // 16-col frags per wave
  const int t = threadIdx.x;
  const int lane = t & 63, w = t >> 6;
  const int lr = lane & 15, lg = lane >> 4;
  const int wm = w / WN, wn = w % WN;
  const int r0 = blockIdx.x * BM, c0 = blockIdx.y * 128;
  u16* ldsA = lds;                 // [BM][64]
  u16* ldsB = lds + BM * 64;       // [128][64]
  const int srow = t >> 3;
  const int scol = (((t & 7) ^ (srow & 7)) * 8);  // inverse-swizzled source granule
  const u16* gA = A + (size_t)(r0 + srow) * KD + scol;
  const u16* gB = Wt + (size_t)(c0 + srow) * KD + scol;
  const int ldst = t * 8;  // linear LDS dest (elements)
  const int gsw = lr & 7;  // read-side XOR for this lane's rows

  for (int k0 = 0; k0 < KD; k0 += 64) {
    #pragma unroll
    for (int r = 0; r < BM / 32; r++)
      gload_lds16(gA + (size_t)(r * 32) * KD + k0, ldsA + r * 2048 + ldst);
    #pragma unroll
    for (int r = 0; r < 4; r++)
      gload_lds16(gB + (size_t)(r * 32) * KD + k0, ldsB + r * 2048 + ldst);
    __syncthreads();
    #pragma unroll
    for (int kk = 0; kk < 2; kk++) {
      bf16x8 a[4], b[NI];
      #pragma unroll
      for (int i = 0; i < 4; i++) {
        int row = wm * 64 + i * 16 + lr;
        a[i] = *(const bf16x8*)(ldsA + row * 64 + (((kk * 4 + lg) ^ gsw) * 8));
      }
      #pragma unroll
      for (int j = 0; j < NI; j++) {
        int row = wn * NI * 16 + j * 16 + lr;
        b[j] = *(const bf16x8*)(ldsB + row * 64 + (((kk * 4 + lg) ^ gsw) * 8));
      }
      #pragma unroll
      for (int i = 0; i < 4; i++)
        #pragma unroll
        for (int j = 0; j < NI; j++)
          acc[i][j] = mfma16(a[i], b[j], acc[i][j]);
    }
    __syncthreads();
  }
}

// ---------------- fused QKV GEMM: N=1536 -> q/k/v buffers ---------------------
__global__ __launch_bounds__(256) void gemm_qkv_kernel(const u16* __restrict__ A,
                                                       const u16* __restrict__ Wt,
                                                       const float* __restrict__ bq,
                                                       const float* __restrict__ bk,
                                                       const float* __restrict__ bv,
                                                       u16* __restrict__ q,
                                                       u16* __restrict__ k,
                                                       u16* __restrict__ v) {
  __shared__ u16 lds[16384];
  f32x4 acc[4][4] = {};
  gemm_core<128, 512>(A, Wt, lds, acc);
  const int lane = threadIdx.x & 63, w = threadIdx.x >> 6;
  const int lr = lane & 15, lg = lane >> 4;
  const int wm = w >> 1, wn = w & 1;
  const int r0 = blockIdx.x * 128, c0 = blockIdx.y * 128;
  #pragma unroll
  for (int j = 0; j < 4; j++) {
    int col = c0 + wn * 64 + j * 16 + lr;
    int sel = col >> 9, cc = col & 511;
    u16* outp = (sel == 0) ? q : (sel == 1) ? k : v;
    const float* bp = (sel == 0) ? bq : (sel == 1) ? bk : bv;
    float bias = bp[cc];
    #pragma unroll
    for (int i = 0; i < 4; i++) {
      int rbase = r0 + wm * 64 + i * 16 + lg * 4;
      #pragma unroll
      for (int r = 0; r < 4; r++)
        outp[(size_t)(rbase + r) * 512 + cc] = f2bf(acc[i][j][r] + bias);
    }
  }
}

// ---------------- FF1 GEMM: relu(h @ W1 + b1), N=2048 ------------------------
__global__ __launch_bounds__(256) void gemm_ff1_kernel(const u16* __restrict__ A,
                                                       const u16* __restrict__ Wt,
                                                       const float* __restrict__ bias,
                                                       u16* __restrict__ out) {
  __shared__ u16 lds[16384];
  f32x4 acc[4][4] = {};
  gemm_core<128, 512>(A, Wt, lds, acc);
  const int lane = threadIdx.x & 63, w = threadIdx.x >> 6;
  const int lr = lane & 15, lg = lane >> 4;
  const int wm = w >> 1, wn = w & 1;
  const int r0 = blockIdx.x * 128, c0 = blockIdx.y * 128;
  #pragma unroll
  for (int j = 0; j < 4; j++) {
    int col = c0 + wn * 64 + j * 16 + lr;
    float bv = bias[col];
    #pragma unroll
    for (int i = 0; i < 4; i++) {
      int rbase = r0 + wm * 64 + i * 16 + lg * 4;
      #pragma unroll
      for (int r = 0; r < 4; r++)
        out[(size_t)(rbase + r) * F + col] = f2bf(fmaxf(acc[i][j][r] + bv, 0.f));
    }
  }
}

// ---------------- residual GEMM: hf += A@W + b (N=512), BM=64 -----------------
template <int KD>
__global__ __launch_bounds__(256) void gemm_resid_kernel(const u16* __restrict__ A,
                                                         const u16* __restrict__ Wt,
                                                         const float* __restrict__ bias,
                                                         float* __restrict__ hf,
                                                         u16* __restrict__ hb) {
  __shared__ u16 lds[12288];
  f32x4 acc[4][4] = {};
  gemm_core<64, KD>(A, Wt, lds, acc);
  const int lane = threadIdx.x & 63, w = threadIdx.x >> 6;
  const int lr = lane & 15, lg = lane >> 4;
  const int wn = w;  // 1x4 wave grid
  const int r0 = blockIdx.x * 64, c0 = blockIdx.y * 128;
  #pragma unroll
  for (int j = 0; j < 2; j++) {
    int col = c0 + wn * 32 + j * 16 + lr;
    float bv = bias[col];
    #pragma unroll
    for (int i = 0; i < 4; i++) {
      int rbase = r0 + i * 16 + lg * 4;
      #pragma unroll
      for (int r = 0; r < 4; r++) {
        size_t idx = (size_t)(rbase + r) * D + col;
        float v = hf[idx] + acc[i][j][r] + bv;
        hf[idx] = v;
        hb[idx] = f2bf(v);
      }
    }
  }
}

// ---------------- V transpose: [B*S][HK] -> [B*H][64][S] ----------------------
__global__ __launch_bounds__(256) void vtrans_kernel(const u16* __restrict__ v,
                                                     u16* __restrict__ vt) {
  __shared__ u16 tile[64][65];
  int bh = blockIdx.x, b = bh >> 3, h = bh & 7;
  int s0 = blockIdx.y * 64;
  int t = threadIdx.x;
  union V16 { uint4 v4[2]; u16 e[16]; };
  {
    int sl = t >> 2, cc = (t & 3) * 16;
    const u16* src = v + (size_t)(b * S + s0 + sl) * HK + h * 64 + cc;
    V16 tv;
    tv.v4[0] = *(const uint4*)src;
    tv.v4[1] = *(const uint4*)(src + 8);
    #pragma unroll
    for (int i = 0; i < 16; i++) tile[sl][cc + i] = tv.e[i];
  }
  __syncthreads();
  {
    int kd = t >> 2, sc = (t & 3) * 16;
    V16 tv;
    #pragma unroll
    for (int i = 0; i < 16; i++) tv.e[i] = tile[sc + i][kd];
    u16* dst = vt + ((size_t)bh * 64 + kd) * S + s0 + sc;
    *(uint4*)dst = tv.v4[0];
    *(uint4*)(dst + 8) = tv.v4[1];
  }
}

// ---------------- flash attention v3: split-KV + VALU diet --------------------
// exp2 domain (v_exp_f32 native), defer-max (THR=8e => 44.36 raw), v_perm
// truncating bf16 pack (bias cancels num/denom), lane-local sum.
__device__ __forceinline__ void load_kv(const u16* kbase, const u16* vbase,
                                        int kv0, int ql, int hi,
                                        bf16x8 (&kf)[4], bf16x8 (&vf)[4]) {
  const u16* kr = kbase + (size_t)(kv0 + ql) * HK;
  #pragma unroll
  for (int kc = 0; kc < 4; kc++) kf[kc] = *(const bf16x8*)(kr + kc * 16 + hi * 8);
  #pragma unroll
  for (int km = 0; km < 2; km++)
    #pragma unroll
    for (int dt = 0; dt < 2; dt++)
      vf[km * 2 + dt] = *(const bf16x8*)(vbase + (size_t)(dt * 32 + ql) * S + kv0 + km * 16 + hi * 8);
}

__global__ __launch_bounds__(256) void attn32_kernel(const u16* __restrict__ q,
                                                     const u16* __restrict__ k,
                                                     const u16* __restrict__ vt,
                                                     u16* __restrict__ o) {
  __shared__ float lds_o[4][64][32];  // [wave][d][q]
  __shared__ float lds_m[4][32];
  __shared__ float lds_l[4][32];
  int bh = blockIdx.x, b = bh >> 3, h = bh & 7;
  int w = threadIdx.x >> 6, lane = threadIdx.x & 63;
  int tile = 63 - (int)blockIdx.y;  // big-work blocks first
  int q0 = tile * 32;
  int ql = lane & 31, hi = lane >> 5;
  int qa = q0 + ql;
  constexpr float c2 = 0.18033688f;   // 0.125 * log2(e)
  constexpr float THR = 44.3614f;     // 8 / c2

  const u16* qrow = q + (size_t)(b * S + qa) * HK + h * 64;
  bf16x8 qf[4];
  #pragma unroll
  for (int kc = 0; kc < 4; kc++) qf[kc] = *(const bf16x8*)(qrow + kc * 16 + hi * 8);

  const u16* kbase = k + (size_t)(b * S) * HK + h * 64;
  const u16* vbase = vt + (size_t)bh * 64 * S;

  f32x16 oacc[2] = {};
  float mraw = -3.0e38f;
  float m2 = mraw * c2;
  float thr = mraw;  // trigger threshold (mraw + THR saturates anyway at first)
  float lsum = 0.f;
  int cnt = (w <= tile) ? ((tile - w) >> 2) + 1 : 0;
  int s = w;

  bf16x8 kf[4], vf[4], kn[4], vn[4];
  if (cnt > 0) load_kv(kbase, vbase, s * 32, ql, hi, kf, vf);

  for (int i = 0; i < cnt; i++) {
    if (i + 1 < cnt) load_kv(kbase, vbase, (s + 4) * 32, ql, hi, kn, vn);
    int kv0 = s * 32;
    f32x16 sacc = {};
    #pragma unroll
    for (int kc = 0; kc < 4; kc++) sacc = mfma32(kf[kc], qf[kc], sacc);

    if (s == tile) {  // diagonal step: causal mask (raw domain)
      #pragma unroll
      for (int r = 0; r < 16; r++) {
        int kva = kv0 + (r & 3) + 8 * (r >> 2) + 4 * hi;
        if (kva > qa) sacc[r] = -3.0e38f;
      }
    }

    float mx = fmaxf(fmaxf(fmaxf(fmaxf(sacc[0], sacc[1]), fmaxf(sacc[2], sacc[3])),
                           fmaxf(fmaxf(sacc[4], sacc[5]), fmaxf(sacc[6], sacc[7]))),
                     fmaxf(fmaxf(fmaxf(sacc[8], sacc[9]), fmaxf(sacc[10], sacc[11])),
                           fmaxf(fmaxf(sacc[12], sacc[13]), fmaxf(sacc[14], sacc[15]))));
    mx = fmaxf(mx, __shfl_xor(mx, 32));
    if (__any(mx > thr)) {  // rare after first step (defer-max)
      float mnew = fmaxf(mraw, mx);
      float corr = exp2f((mraw - mnew) * c2);
      mraw = mnew;
      m2 = mraw * c2;
      thr = mraw + THR;
      lsum *= corr;
      #pragma unroll
      for (int dt = 0; dt < 2; dt++)
        #pragma unroll
        for (int r = 0; r < 16; r++) oacc[dt][r] *= corr;
    }

    float p[16];
    #pragma unroll
    for (int r = 0; r < 16; r++) p[r] = exp2f(fmaf(sacc[r], c2, -m2));
    lsum += (((p[0] + p[1]) + (p[2] + p[3])) + ((p[4] + p[5]) + (p[6] + p[7])))
          + (((p[8] + p[9]) + (p[10] + p[11])) + ((p[12] + p[13]) + (p[14] + p[15])));

    #pragma unroll
    for (int km = 0; km < 2; km++) {
      int base = 8 * km;
      u32 a0_01 = pk2t(p[base + 0], p[base + 1]);
      u32 a0_23 = pk2t(p[base + 2], p[base + 3]);
      u32 a1_01 = pk2t(p[base + 4], p[base + 5]);
      u32 a1_23 = pk2t(p[base + 6], p[base + 7]);
      u32 send1 = hi ? a0_01 : a1_01;
      u32 send2 = hi ? a0_23 : a1_23;
      u32 recv1 = __shfl_xor(send1, 32);
      u32 recv2 = __shfl_xor(send2, 32);
      union { u32 wd[4]; bf16x8 v; } pf;
      if (hi == 0) { pf.wd[0] = a0_01; pf.wd[1] = a0_23; pf.wd[2] = recv1; pf.wd[3] = recv2; }
      else         { pf.wd[0] = recv1; pf.wd[1] = recv2; pf.wd[2] = a1_01; pf.wd[3] = a1_23; }
      oacc[0] = mfma32(vf[km * 2 + 0], pf.v, oacc[0]);
      oacc[1] = mfma32(vf[km * 2 + 1], pf.v, oacc[1]);
    }
    #pragma unroll
    for (int j = 0; j < 4; j++) { kf[j] = kn[j]; vf[j] = vn[j]; }
    s += 4;
  }
  float lrun = lsum + __shfl_xor(lsum, 32);

  if (hi == 0) { lds_m[w][ql] = mraw; lds_l[w][ql] = lrun; }
  #pragma unroll
  for (int dt = 0; dt < 2; dt++)
    #pragma unroll
    for (int r = 0; r < 16; r++) {
      int d = dt * 32 + (r & 3) + 8 * (r >> 2) + 4 * hi;
      lds_o[w][d][ql] = oacc[dt][r];
    }
  __syncthreads();

  // combine partials (base-2 weights)
  float m0 = lds_m[0][ql], m1 = lds_m[1][ql], m2c = lds_m[2][ql], m3 = lds_m[3][ql];
  float Mx = fmaxf(fmaxf(m0, m1), fmaxf(m2c, m3));
  float s0 = exp2f((m0 - Mx) * c2), s1 = exp2f((m1 - Mx) * c2);
  float s2 = exp2f((m2c - Mx) * c2), s3 = exp2f((m3 - Mx) * c2);
  float Ls = lds_l[0][ql] * s0 + lds_l[1][ql] * s1 + lds_l[2][ql] * s2 + lds_l[3][ql] * s3;
  float inv = 1.0f / Ls;
  int dbase = w * 16 + hi * 8;
  union { uint4 u4; u16 e[8]; } outv;
  #pragma unroll
  for (int j = 0; j < 8; j++) {
    int d = dbase + j;
    float v = (lds_o[0][d][ql] * s0 + lds_o[1][d][ql] * s1 +
               lds_o[2][d][ql] * s2 + lds_o[3][d][ql] * s3) * inv;
    outv.e[j] = f2bf(v);
  }
  *(uint4*)(o + (size_t)(b * S + qa) * HK + h * 64 + dbase) = outv.u4;
}

extern "C" void kernel_launch(void* const* d_in, const int* in_sizes, int n_in,
                              void* d_out, int out_size, void* d_ws, size_t ws_size,
                              hipStream_t stream) {
  const int* x = (const int*)d_in[0];
  const float* emb = (const float*)d_in[1];
  const float* pos = (const float*)d_in[2];
  const float* Wq = (const float*)d_in[3];
  const float* bq = (const float*)d_in[4];
  const float* Wk = (const float*)d_in[5];
  const float* bk = (const float*)d_in[6];
  const float* Wv = (const float*)d_in[7];
  const float* bv = (const float*)d_in[8];
  const float* Wo = (const float*)d_in[9];
  const float* bo = (const float*)d_in[10];
  const float* W1 = (const float*)d_in[11];
  const float* b1 = (const float*)d_in[12];
  const float* W2 = (const float*)d_in[13];
  const float* b2 = (const float*)d_in[14];
  float* hf = (float*)d_out;

  char* p = (char*)d_ws;
  const size_t SZ_MD = (size_t)M * D * 2;  // 4MB
  u16* h_bf = (u16*)p;  p += SZ_MD;
  u16* q_bf = (u16*)p;  p += SZ_MD;
  u16* k_bf = (u16*)p;  p += SZ_MD;
  u16* v_bf = (u16*)p;  p += SZ_MD;
  u16* vt_bf = (u16*)p; p += SZ_MD;
  u16* o_bf = (u16*)p;  p += SZ_MD;
  u16* ff_bf = (u16*)p; p += (size_t)M * F * 2;
  u16* WqkvT = (u16*)p; p += (size_t)L * D * (3 * HK) * 2;  // [L][1536][512]
  u16* WoT = (u16*)p;   p += (size_t)L * HK * D * 2;
  u16* W1T = (u16*)p;   p += (size_t)L * D * F * 2;
  u16* W2T = (u16*)p;   p += (size_t)L * F * D * 2;

  dim3 tb(32, 8);
  const int QKV_L = 3 * HK * D;  // per-layer stride of fused qkv weights
  wtrans_kernel<<<dim3(D / 32, HK / 32, L), tb, 0, stream>>>(Wq, WqkvT, D, HK, QKV_L);
  wtrans_kernel<<<dim3(D / 32, HK / 32, L), tb, 0, stream>>>(Wk, WqkvT + HK * D, D, HK, QKV_L);
  wtrans_kernel<<<dim3(D / 32, HK / 32, L), tb, 0, stream>>>(Wv, WqkvT + 2 * HK * D, D, HK, QKV_L);
  wtrans_kernel<<<dim3(HK / 32, D / 32, L), tb, 0, stream>>>(Wo, WoT, HK, D, HK * D);
  wtrans_kernel<<<dim3(D / 32, F / 32, L), tb, 0, stream>>>(W1, W1T, D, F, D * F);
  wtrans_kernel<<<dim3(F / 32, D / 32, L), tb, 0, stream>>>(W2, W2T, F, D, F * D);

  embed_kernel<<<(M * D / 4) / 256, 256, 0, stream>>>(x, emb, pos, hf, h_bf);

  for (int l = 0; l < L; ++l) {
    gemm_qkv_kernel<<<dim3(M / 128, (3 * HK) / 128), 256, 0, stream>>>(
        h_bf, WqkvT + (size_t)l * QKV_L, bq + l * HK, bk + l * HK, bv + l * HK,
        q_bf, k_bf, v_bf);
    vtrans_kernel<<<dim3(B * H, S / 64), 256, 0, stream>>>(v_bf, vt_bf);
    attn32_kernel<<<dim3(B * H, 64), 256, 0, stream>>>(q_bf, k_bf, vt_bf, o_bf);
    gemm_resid_kernel<512><<<dim3(M / 64, D / 128), 256, 0, stream>>>(
        o_bf, WoT + (size_t)l * HK * D, bo + l * D, hf, h_bf);
    gemm_ff1_kernel<<<dim3(M / 128, F / 128), 256, 0, stream>>>(
        h_bf, W1T + (size_t)l * D * F, b1 + l * F, ff_bf);
    gemm_resid_kernel<2048><<<dim3(M / 64, D / 128), 256, 0, stream>>>(
        ff_bf, W2T + (size_t)l * F * D, b2 + l * D, hf, h_bf);
  }
}